// Round 1
// 685.597 us; speedup vs baseline: 1.0670x; 1.0670x over previous
//
#include <hip/hip_runtime.h>
#include <hip/hip_fp16.h>

// LightGCN on MI355X — bucket-sort CSR build + 8-edge-parallel SpMM, fp16 gathers.
// final = (E + A E + A^2 E + A^3 E) / 4,  E = concat(user_emb, item_emb)
//
// R6 changes vs R5:
//  - bucket_scatter: LDS-staged counting sort per block, coalesced run writeback
//    (binary search over local scan). Kills the 3.6x write amplification
//    (WRITE 137MB -> ~55MB) of the old random 8B cursor writes.
//    NB 2048->512 (RPB 586), CE 16384->6144 to fit 48KB staging in static LDS.
//  - spmm: 1 row/wave, lane=(edge e8=lane>>3, dim d=lane&7). 8 gathers of 128B
//    in flight per step, NO per-edge ds_bpermute broadcast chain (old version
//    serialized ~500cy latency per edge). Butterfly reduce once per row.
//  - fine_sort: 512 blocks x 1024 threads, 640-entry scan (RPB=586).

#define NU 200000
#define NI 100000
#define NN 300000          // NU + NI
#define DD 64
#define NE 4800000
#define NB 512             // coarse buckets
#define RPB 586            // rows per bucket: 512*586 = 300032 >= NN
#define NRPAD 640          // RPB padded for fine_sort scan
#define CE_HIST 8192       // edges per block, bucket_hist  (586 blocks)
#define CE_SCAT 6144       // edges per block, bucket_scatter (782 blocks)
#define EPT (CE_SCAT / 1024)   // 6 edges per thread in scatter

// ---- Phase 1: bucket histogram (LDS pre-aggregated, int4 loads) ---------

__global__ void bucket_hist(const int* __restrict__ rows, int* __restrict__ bcnt) {
    __shared__ int h[NB];
    int tid = threadIdx.x;
    for (int i = tid; i < NB; i += 1024) h[i] = 0;
    __syncthreads();
    const int4* r4 = (const int4*)rows;
    int q0 = blockIdx.x * (CE_HIST / 4);
    for (int k = 0; k < CE_HIST / 4096; ++k) {
        int q = q0 + k * 1024 + tid;
        if (q < NE / 4) {
            int4 r = r4[q];
            atomicAdd(&h[(unsigned)r.x / RPB], 1);
            atomicAdd(&h[(unsigned)r.y / RPB], 1);
            atomicAdd(&h[(unsigned)r.z / RPB], 1);
            atomicAdd(&h[(unsigned)r.w / RPB], 1);
        }
    }
    __syncthreads();
    for (int i = tid; i < NB; i += 1024) {
        int c = h[i];
        if (c) atomicAdd(&bcnt[i], c);
    }
}

// ---- Phase 2a: exclusive scan of 512 bucket counts ----------------------

__global__ void bucket_scan(const int* __restrict__ bcnt, int* __restrict__ bbase,
                            int* __restrict__ gcursor) {
    __shared__ int sh[NB];
    int t = threadIdx.x;          // 512 threads
    int v = bcnt[t];
    sh[t] = v;
    __syncthreads();
    for (int o = 1; o < NB; o <<= 1) {
        int x = (t >= o) ? sh[t - o] : 0;
        __syncthreads();
        sh[t] += x;
        __syncthreads();
    }
    int excl = sh[t] - v;
    bbase[t] = excl;
    gcursor[t] = excl;
    if (t == NB - 1) bbase[NB] = NE;
}

// ---- Phase 2b: LDS-staged coarse sort, coalesced run writeback ----------
// record: x = (rowlocal << 19) | col   (rowlocal < 586 < 2^10, col < 2^19)
//         y = float bits of val

__global__ void bucket_scatter(const int* __restrict__ rows, const int* __restrict__ cols,
                               const float* __restrict__ vals,
                               int* __restrict__ gcursor, int2* __restrict__ recs) {
    __shared__ int  cnt[NB];        // hist, then reused as staging cursor
    __shared__ int  lofs[NB + 1];   // local exclusive scan (+ total sentinel)
    __shared__ int  dlt[NB];        // global_base - local_base per bucket
    __shared__ int2 stg[CE_SCAT];   // 48KB staging
    int tid = threadIdx.x;          // 1024 threads
    if (tid < NB) cnt[tid] = 0;
    __syncthreads();
    int e0 = blockIdx.x * CE_SCAT;
    int r[EPT];
    #pragma unroll
    for (int k = 0; k < EPT; ++k) {
        int e = e0 + k * 1024 + tid;
        r[k] = -1;
        if (e < NE) {
            r[k] = rows[e];
            atomicAdd(&cnt[(unsigned)r[k] / RPB], 1);
        }
    }
    __syncthreads();
    // inclusive scan of cnt into lofs (512 entries, first 512 threads)
    if (tid < NB) lofs[tid] = cnt[tid];
    __syncthreads();
    for (int o = 1; o < NB; o <<= 1) {
        int x = 0;
        if (tid < NB && tid >= o) x = lofs[tid - o];
        __syncthreads();
        if (tid < NB) lofs[tid] += x;
        __syncthreads();
    }
    // convert to exclusive, reserve global run, reset cursor
    if (tid < NB) {
        int incl = lofs[tid];
        int c = cnt[tid];
        int excl = incl - c;
        int gb = c ? atomicAdd(&gcursor[tid], c) : 0;
        lofs[tid] = excl;
        dlt[tid] = gb - excl;
        cnt[tid] = 0;
        if (tid == NB - 1) lofs[NB] = incl;   // total staged in this block
    }
    __syncthreads();
    // stage records bucket-sorted in LDS
    #pragma unroll
    for (int k = 0; k < EPT; ++k) {
        int e = e0 + k * 1024 + tid;
        if (e < NE) {
            int rr = r[k];
            int b = (unsigned)rr / RPB;
            int p = lofs[b] + atomicAdd(&cnt[b], 1);
            int rl = rr - b * RPB;
            stg[p] = make_int2((rl << 19) | cols[e], __float_as_int(vals[e]));
        }
    }
    __syncthreads();
    // coalesced writeback: consecutive i -> consecutive global pos within runs
    int total = lofs[NB];
    for (int i = tid; i < total; i += 1024) {
        int b = 0;
        #pragma unroll
        for (int s = NB >> 1; s > 0; s >>= 1)
            if (lofs[b + s] <= i) b += s;     // greatest b with lofs[b] <= i
        recs[dlt[b] + i] = stg[i];
    }
}

// ---- Phase 3: per-bucket LDS counting sort -> final CSR -----------------

__global__ void fine_sort(const int* __restrict__ bbase, const int2* __restrict__ recs,
                          int2* __restrict__ edges, int* __restrict__ off) {
    __shared__ int cnt[NRPAD];
    __shared__ int scn[NRPAD];
    __shared__ int cur[NRPAD];
    int b = blockIdx.x, tid = threadIdx.x;   // 1024 threads
    int e0 = bbase[b], e1 = bbase[b + 1];
    if (tid < NRPAD) cnt[tid] = 0;
    __syncthreads();
    for (int e = e0 + tid; e < e1; e += 1024)
        atomicAdd(&cnt[recs[e].x >> 19], 1);
    __syncthreads();
    int v = 0;
    if (tid < NRPAD) { v = cnt[tid]; scn[tid] = v; }
    __syncthreads();
    for (int o = 1; o < NRPAD; o <<= 1) {
        int x = 0;
        if (tid < NRPAD && tid >= o) x = scn[tid - o];
        __syncthreads();
        if (tid < NRPAD) scn[tid] += x;
        __syncthreads();
    }
    if (tid < NRPAD) {
        int excl = e0 + scn[tid] - v;
        cur[tid] = excl;
        if (tid < RPB) {
            int row = b * RPB + tid;
            if (row < NN) off[row] = excl;
        }
    }
    if (b == 0 && tid == 0) off[NN] = NE;
    __syncthreads();
    for (int e = e0 + tid; e < e1; e += 1024) {
        int2 rc = recs[e];
        int rl = rc.x >> 19;
        int p = atomicAdd(&cur[rl], 1);
        edges[p] = make_int2(rc.x & 0x7FFFF, rc.y);   // (col, val-bits)
    }
}

// ---- E (fp32 concat view) -> h0 (fp16, [NN][64]) ------------------------

__global__ void e_to_h(const float4* __restrict__ ue4, const float4* __restrict__ ie4,
                       uint2* __restrict__ h) {
    int i = blockIdx.x * blockDim.x + threadIdx.x;   // over NN*16 float4-groups
    if (i >= NN * 16) return;
    float4 v = (i < NU * 16) ? ue4[i] : ie4[i - NU * 16];
    __half2 a = __float22half2_rn(make_float2(v.x, v.y));
    __half2 b = __float22half2_rn(make_float2(v.z, v.w));
    h[i] = make_uint2(*(unsigned*)&a, *(unsigned*)&b);
}

// ---- SpMM: 1 row/wave; lane = (e8 = lane>>3 edge slot, d = lane&7 dims) ----
// 8 edges gathered in parallel per step, each by 8 lanes x 16B (128B row).
// No per-edge broadcast shuffles; butterfly reduce over e8 once per row.
// MODE 0: acc = E32[row] + sum;  1: acc += sum;  2: acc = (acc+sum)*0.25.

template <int MODE>
__global__ void spmm8_kernel(const int* __restrict__ off, const int2* __restrict__ edges,
                             const uint4* __restrict__ h8,    // fp16 table, [NN][8] x 16B
                             uint4* __restrict__ nxtH8,       // fp16 output
                             float* __restrict__ acc,
                             const float* __restrict__ ue, const float* __restrict__ ie2) {
    int row  = (blockIdx.x * blockDim.x + threadIdx.x) >> 6;  // one row per wave
    int lane = threadIdx.x & 63;
    int e8   = lane >> 3;     // edge slot 0..7
    int d    = lane & 7;      // dim group (8 halves = 16B)
    if (row >= NN) return;

    int start = off[row], end = off[row + 1];
    float s0 = 0.f, s1 = 0.f, s2 = 0.f, s3 = 0.f;
    float s4 = 0.f, s5 = 0.f, s6 = 0.f, s7 = 0.f;

    for (int base = start; base < end; base += 8) {
        int e = base + e8;
        if (e < end) {
            int2 ev = edges[e];                       // 8 lanes same rec: 64B/wave
            float v = __int_as_float(ev.y);
            uint4 hx = h8[(size_t)ev.x * 8 + d];      // 8 lanes x 16B = 128B row
            float2 f0 = __half22float2(*(__half2*)&hx.x);
            float2 f1 = __half22float2(*(__half2*)&hx.y);
            float2 f2 = __half22float2(*(__half2*)&hx.z);
            float2 f3 = __half22float2(*(__half2*)&hx.w);
            s0 += v * f0.x; s1 += v * f0.y;
            s2 += v * f1.x; s3 += v * f1.y;
            s4 += v * f2.x; s5 += v * f2.y;
            s6 += v * f3.x; s7 += v * f3.y;
        }
    }

    // reduce over the 8 edge slots (lanes strided by 8 share d)
    #pragma unroll
    for (int o = 8; o < 64; o <<= 1) {
        s0 += __shfl_xor(s0, o); s1 += __shfl_xor(s1, o);
        s2 += __shfl_xor(s2, o); s3 += __shfl_xor(s3, o);
        s4 += __shfl_xor(s4, o); s5 += __shfl_xor(s5, o);
        s6 += __shfl_xor(s6, o); s7 += __shfl_xor(s7, o);
    }

    if (e8 != 0) return;   // lanes 0..7 own the row output
    if (MODE != 2) {
        __half2 q0 = __float22half2_rn(make_float2(s0, s1));
        __half2 q1 = __float22half2_rn(make_float2(s2, s3));
        __half2 q2 = __float22half2_rn(make_float2(s4, s5));
        __half2 q3 = __float22half2_rn(make_float2(s6, s7));
        nxtH8[(size_t)row * 8 + d] = make_uint4(*(unsigned*)&q0, *(unsigned*)&q1,
                                                *(unsigned*)&q2, *(unsigned*)&q3);
    }
    float4* acc4 = (float4*)acc;
    size_t o16 = (size_t)row * 16 + 2 * d;
    if (MODE == 0) {
        const float* p = (row < NU) ? ue : ie2;
        const float4* pe = (const float4*)(p + (size_t)row * DD);
        float4 a0 = pe[2 * d], a1 = pe[2 * d + 1];
        acc4[o16]     = make_float4(a0.x + s0, a0.y + s1, a0.z + s2, a0.w + s3);
        acc4[o16 + 1] = make_float4(a1.x + s4, a1.y + s5, a1.z + s6, a1.w + s7);
    } else if (MODE == 1) {
        float4 a0 = acc4[o16], a1 = acc4[o16 + 1];
        acc4[o16]     = make_float4(a0.x + s0, a0.y + s1, a0.z + s2, a0.w + s3);
        acc4[o16 + 1] = make_float4(a1.x + s4, a1.y + s5, a1.z + s6, a1.w + s7);
    } else {
        float4 a0 = acc4[o16], a1 = acc4[o16 + 1];
        acc4[o16]     = make_float4((a0.x + s0) * 0.25f, (a0.y + s1) * 0.25f,
                                    (a0.z + s2) * 0.25f, (a0.w + s3) * 0.25f);
        acc4[o16 + 1] = make_float4((a1.x + s4) * 0.25f, (a1.y + s5) * 0.25f,
                                    (a1.z + s6) * 0.25f, (a1.w + s7) * 0.25f);
    }
}

// ---- launch -------------------------------------------------------------

extern "C" void kernel_launch(void* const* d_in, const int* in_sizes, int n_in,
                              void* d_out, int out_size, void* d_ws, size_t ws_size,
                              hipStream_t stream) {
    const float* ue   = (const float*)d_in[0];
    const float* ie   = (const float*)d_in[1];
    const int*   rows = (const int*)d_in[2];
    const int*   cols = (const int*)d_in[3];
    const float* vals = (const float*)d_in[4];
    float* acc = (float*)d_out;

    char* ws = (char*)d_ws;
    size_t p = 0;
    auto alloc = [&](size_t bytes) -> void* {
        p = (p + 255) & ~(size_t)255;
        void* r = ws + p;
        p += bytes;
        return r;
    };
    int2*  edges   = (int2*) alloc((size_t)NE * 8);         // 38.4 MB final CSR
    uint2* h0      = (uint2*)alloc((size_t)NN * 16 * 8);    // 38.4 MB fp16 table
    uint2* h1      = (uint2*)alloc((size_t)NN * 16 * 8);    // 38.4 MB fp16 table
    int*   bcnt    = (int*)  alloc((size_t)NB * 4);
    int*   bbase   = (int*)  alloc((size_t)(NB + 1) * 4);
    int*   gcursor = (int*)  alloc((size_t)NB * 4);
    int*   off     = (int*)  alloc((size_t)(NN + 1) * 4);
    // recs (38.4 MB) aliases h1: dead after fine_sort, h1 first written by spmm<0>
    int2*  recs = (int2*)h1;
    // h2 aliases h0: h0 dead after spmm<0> (spmm<1> gathers h1 only)
    uint2* h2 = h0;

    // 1. CSR build: hist -> scan -> LDS-staged coarse scatter -> fine sort
    hipMemsetAsync(bcnt, 0, (size_t)NB * 4, stream);
    bucket_hist   <<<(NE + CE_HIST - 1) / CE_HIST, 1024, 0, stream>>>(rows, bcnt);
    bucket_scan   <<<1, NB, 0, stream>>>(bcnt, bbase, gcursor);
    bucket_scatter<<<(NE + CE_SCAT - 1) / CE_SCAT, 1024, 0, stream>>>(rows, cols, vals, gcursor, recs);
    fine_sort     <<<NB, 1024, 0, stream>>>(bbase, recs, edges, off);

    // 2. E -> fp16 table (after fine_sort: recs aliases h1, not h0 — safe order)
    const float* ie2 = ie - (size_t)NU * DD;   // pre-shifted item base for concat view
    e_to_h<<<(NN * 16 + 255) / 256, 256, 0, stream>>>(
        (const float4*)ue, (const float4*)ie2 + (size_t)NU * 16, h0);

    // 3. three propagation layers; acc (= d_out) fused, final /4 fused into last
    const int spmm_blocks = NN / 4;   // 1 row/wave, 4 waves/block
    spmm8_kernel<0><<<spmm_blocks, 256, 0, stream>>>(off, edges, (const uint4*)h0, (uint4*)h1, acc, ue, ie2);
    spmm8_kernel<1><<<spmm_blocks, 256, 0, stream>>>(off, edges, (const uint4*)h1, (uint4*)h2, acc, ue, ie2);
    spmm8_kernel<2><<<spmm_blocks, 256, 0, stream>>>(off, edges, (const uint4*)h2, (uint4*)h1, acc, ue, ie2);
}

// Round 2
// 671.063 us; speedup vs baseline: 1.0901x; 1.0217x over previous
//
#include <hip/hip_runtime.h>
#include <hip/hip_fp16.h>

// LightGCN on MI355X — bucket-sort CSR build + 16-edge-parallel SpMM, fp16 gathers.
// final = (E + A E + A^2 E + A^3 E) / 4,  E = concat(user_emb, item_emb)
//
// R7 changes vs R6 (spmm was latency-bound: 38% HBM, 44% VALU, 78% occ):
//  - spmm lane map e16 x d4: 16 edges gathered in parallel per wave step
//    (avg degree = 16 -> average row now completes in ONE iteration of the
//    serial edge-load -> gather chain, was two).
//  - recursive-halving reduce-scatter over edge slots: 15 shuffles (vs 64
//    butterfly), ends with all 64 lanes owning one output element each ->
//    fully parallel epilogue (fp16 store + fp32 acc RMW).
//  - nontemporal hints on streaming traffic (edges, acc, E, h writes) to
//    stop evicting the 38.4MB gather table from the 4MB/XCD L2.

#define NU 200000
#define NI 100000
#define NN 300000          // NU + NI
#define DD 64
#define NE 4800000
#define NB 512             // coarse buckets
#define RPB 586            // rows per bucket: 512*586 = 300032 >= NN
#define NRPAD 640          // RPB padded for fine_sort scan
#define CE_HIST 8192       // edges per block, bucket_hist  (586 blocks)
#define CE_SCAT 6144       // edges per block, bucket_scatter (782 blocks)
#define EPT (CE_SCAT / 1024)   // 6 edges per thread in scatter

// ---- Phase 1: bucket histogram (LDS pre-aggregated, int4 loads) ---------

__global__ void bucket_hist(const int* __restrict__ rows, int* __restrict__ bcnt) {
    __shared__ int h[NB];
    int tid = threadIdx.x;
    for (int i = tid; i < NB; i += 1024) h[i] = 0;
    __syncthreads();
    const int4* r4 = (const int4*)rows;
    int q0 = blockIdx.x * (CE_HIST / 4);
    for (int k = 0; k < CE_HIST / 4096; ++k) {
        int q = q0 + k * 1024 + tid;
        if (q < NE / 4) {
            int4 r = r4[q];
            atomicAdd(&h[(unsigned)r.x / RPB], 1);
            atomicAdd(&h[(unsigned)r.y / RPB], 1);
            atomicAdd(&h[(unsigned)r.z / RPB], 1);
            atomicAdd(&h[(unsigned)r.w / RPB], 1);
        }
    }
    __syncthreads();
    for (int i = tid; i < NB; i += 1024) {
        int c = h[i];
        if (c) atomicAdd(&bcnt[i], c);
    }
}

// ---- Phase 2a: exclusive scan of 512 bucket counts ----------------------

__global__ void bucket_scan(const int* __restrict__ bcnt, int* __restrict__ bbase,
                            int* __restrict__ gcursor) {
    __shared__ int sh[NB];
    int t = threadIdx.x;          // 512 threads
    int v = bcnt[t];
    sh[t] = v;
    __syncthreads();
    for (int o = 1; o < NB; o <<= 1) {
        int x = (t >= o) ? sh[t - o] : 0;
        __syncthreads();
        sh[t] += x;
        __syncthreads();
    }
    int excl = sh[t] - v;
    bbase[t] = excl;
    gcursor[t] = excl;
    if (t == NB - 1) bbase[NB] = NE;
}

// ---- Phase 2b: LDS-staged coarse sort, coalesced run writeback ----------
// record: x = (rowlocal << 19) | col   (rowlocal < 586 < 2^10, col < 2^19)
//         y = float bits of val

__global__ void bucket_scatter(const int* __restrict__ rows, const int* __restrict__ cols,
                               const float* __restrict__ vals,
                               int* __restrict__ gcursor, int2* __restrict__ recs) {
    __shared__ int  cnt[NB];        // hist, then reused as staging cursor
    __shared__ int  lofs[NB + 1];   // local exclusive scan (+ total sentinel)
    __shared__ int  dlt[NB];        // global_base - local_base per bucket
    __shared__ int2 stg[CE_SCAT];   // 48KB staging
    int tid = threadIdx.x;          // 1024 threads
    if (tid < NB) cnt[tid] = 0;
    __syncthreads();
    int e0 = blockIdx.x * CE_SCAT;
    int r[EPT];
    #pragma unroll
    for (int k = 0; k < EPT; ++k) {
        int e = e0 + k * 1024 + tid;
        r[k] = -1;
        if (e < NE) {
            r[k] = rows[e];
            atomicAdd(&cnt[(unsigned)r[k] / RPB], 1);
        }
    }
    __syncthreads();
    // inclusive scan of cnt into lofs (512 entries, first 512 threads)
    if (tid < NB) lofs[tid] = cnt[tid];
    __syncthreads();
    for (int o = 1; o < NB; o <<= 1) {
        int x = 0;
        if (tid < NB && tid >= o) x = lofs[tid - o];
        __syncthreads();
        if (tid < NB) lofs[tid] += x;
        __syncthreads();
    }
    // convert to exclusive, reserve global run, reset cursor
    if (tid < NB) {
        int incl = lofs[tid];
        int c = cnt[tid];
        int excl = incl - c;
        int gb = c ? atomicAdd(&gcursor[tid], c) : 0;
        lofs[tid] = excl;
        dlt[tid] = gb - excl;
        cnt[tid] = 0;
        if (tid == NB - 1) lofs[NB] = incl;   // total staged in this block
    }
    __syncthreads();
    // stage records bucket-sorted in LDS
    #pragma unroll
    for (int k = 0; k < EPT; ++k) {
        int e = e0 + k * 1024 + tid;
        if (e < NE) {
            int rr = r[k];
            int b = (unsigned)rr / RPB;
            int p = lofs[b] + atomicAdd(&cnt[b], 1);
            int rl = rr - b * RPB;
            stg[p] = make_int2((rl << 19) | cols[e], __float_as_int(vals[e]));
        }
    }
    __syncthreads();
    // coalesced writeback: consecutive i -> consecutive global pos within runs
    int total = lofs[NB];
    for (int i = tid; i < total; i += 1024) {
        int b = 0;
        #pragma unroll
        for (int s = NB >> 1; s > 0; s >>= 1)
            if (lofs[b + s] <= i) b += s;     // greatest b with lofs[b] <= i
        recs[dlt[b] + i] = stg[i];
    }
}

// ---- Phase 3: per-bucket LDS counting sort -> final CSR -----------------

__global__ void fine_sort(const int* __restrict__ bbase, const int2* __restrict__ recs,
                          int2* __restrict__ edges, int* __restrict__ off) {
    __shared__ int cnt[NRPAD];
    __shared__ int scn[NRPAD];
    __shared__ int cur[NRPAD];
    int b = blockIdx.x, tid = threadIdx.x;   // 1024 threads
    int e0 = bbase[b], e1 = bbase[b + 1];
    if (tid < NRPAD) cnt[tid] = 0;
    __syncthreads();
    for (int e = e0 + tid; e < e1; e += 1024)
        atomicAdd(&cnt[recs[e].x >> 19], 1);
    __syncthreads();
    int v = 0;
    if (tid < NRPAD) { v = cnt[tid]; scn[tid] = v; }
    __syncthreads();
    for (int o = 1; o < NRPAD; o <<= 1) {
        int x = 0;
        if (tid < NRPAD && tid >= o) x = scn[tid - o];
        __syncthreads();
        if (tid < NRPAD) scn[tid] += x;
        __syncthreads();
    }
    if (tid < NRPAD) {
        int excl = e0 + scn[tid] - v;
        cur[tid] = excl;
        if (tid < RPB) {
            int row = b * RPB + tid;
            if (row < NN) off[row] = excl;
        }
    }
    if (b == 0 && tid == 0) off[NN] = NE;
    __syncthreads();
    for (int e = e0 + tid; e < e1; e += 1024) {
        int2 rc = recs[e];
        int rl = rc.x >> 19;
        int p = atomicAdd(&cur[rl], 1);
        edges[p] = make_int2(rc.x & 0x7FFFF, rc.y);   // (col, val-bits)
    }
}

// ---- E (fp32 concat view) -> h0 (fp16, [NN][64]) ------------------------

__global__ void e_to_h(const float4* __restrict__ ue4, const float4* __restrict__ ie4,
                       uint2* __restrict__ h) {
    int i = blockIdx.x * blockDim.x + threadIdx.x;   // over NN*16 float4-groups
    if (i >= NN * 16) return;
    float4 v = (i < NU * 16) ? ue4[i] : ie4[i - NU * 16];
    __half2 a = __float22half2_rn(make_float2(v.x, v.y));
    __half2 b = __float22half2_rn(make_float2(v.z, v.w));
    h[i] = make_uint2(*(unsigned*)&a, *(unsigned*)&b);
}

// ---- SpMM: 1 row/wave; lane = (e = lane>>2 edge slot, d = lane&3 dims) ----
// 16 edges gathered in parallel per step; each edge's 128B fp16 row read by
// 4 lanes x 2 dwordx4. Avg degree 16 -> one iteration per row on average.
// Reduce over edge slots via recursive-halving reduce-scatter (15 shuffles);
// afterwards lane e*4+d holds output element d*16 + bitrev4(e) -> all 64
// lanes participate in the epilogue.
// MODE 0: acc = E32[row] + sum;  1: acc += sum;  2: acc = (acc+sum)*0.25.

template <int MODE>
__global__ void spmm16_kernel(const int* __restrict__ off, const int2* __restrict__ edges,
                              const uint4* __restrict__ h8,   // fp16 table, [NN][8] x 16B
                              __half* __restrict__ nxtH,      // fp16 output, elementwise
                              float* __restrict__ acc,
                              const float* __restrict__ ue, const float* __restrict__ ie2) {
    int row  = (blockIdx.x * blockDim.x + threadIdx.x) >> 6;  // one row per wave
    int lane = threadIdx.x & 63;
    int e    = lane >> 2;     // edge slot 0..15
    int d    = lane & 3;      // dim quarter (16 halves = 32B)
    if (row >= NN) return;

    int start = off[row], end = off[row + 1];

    float s[16];
    #pragma unroll
    for (int k = 0; k < 16; ++k) s[k] = 0.f;

    for (int base = start; base < end; base += 16) {
        int ei = base + e;
        if (ei < end) {
            long long evl = __builtin_nontemporal_load((const long long*)&edges[ei]);
            int   c = (int)(unsigned)evl;
            float v = __int_as_float((int)(evl >> 32));
            const uint4* hp = &h8[(size_t)c * 8 + d * 2];
            uint4 ha = hp[0];              // halves d*16 + 0..7
            uint4 hb = hp[1];              // halves d*16 + 8..15
            float2 f0 = __half22float2(*(__half2*)&ha.x);
            float2 f1 = __half22float2(*(__half2*)&ha.y);
            float2 f2 = __half22float2(*(__half2*)&ha.z);
            float2 f3 = __half22float2(*(__half2*)&ha.w);
            s[0] += v * f0.x; s[1] += v * f0.y;
            s[2] += v * f1.x; s[3] += v * f1.y;
            s[4] += v * f2.x; s[5] += v * f2.y;
            s[6] += v * f3.x; s[7] += v * f3.y;
            float2 g0 = __half22float2(*(__half2*)&hb.x);
            float2 g1 = __half22float2(*(__half2*)&hb.y);
            float2 g2 = __half22float2(*(__half2*)&hb.z);
            float2 g3 = __half22float2(*(__half2*)&hb.w);
            s[8]  += v * g0.x; s[9]  += v * g0.y;
            s[10] += v * g1.x; s[11] += v * g1.y;
            s[12] += v * g2.x; s[13] += v * g2.y;
            s[14] += v * g3.x; s[15] += v * g3.y;
        }
    }

    // recursive-halving reduce-scatter over the 16 edge slots (lane bits 2..5).
    // At each step, lanes with the bit set keep the upper half of their range.
    {
        bool up = (lane & 4) != 0;
        #pragma unroll
        for (int k = 0; k < 8; ++k) {
            float keep = up ? s[k + 8] : s[k];
            float give = up ? s[k] : s[k + 8];
            s[k] = keep + __shfl_xor(give, 4);
        }
    }
    {
        bool up = (lane & 8) != 0;
        #pragma unroll
        for (int k = 0; k < 4; ++k) {
            float keep = up ? s[k + 4] : s[k];
            float give = up ? s[k] : s[k + 4];
            s[k] = keep + __shfl_xor(give, 8);
        }
    }
    {
        bool up = (lane & 16) != 0;
        #pragma unroll
        for (int k = 0; k < 2; ++k) {
            float keep = up ? s[k + 2] : s[k];
            float give = up ? s[k] : s[k + 2];
            s[k] = keep + __shfl_xor(give, 16);
        }
    }
    {
        bool up = (lane & 32) != 0;
        float keep = up ? s[1] : s[0];
        float give = up ? s[0] : s[1];
        s[0] = keep + __shfl_xor(give, 32);
    }

    // lane e*4+d now holds element d*16 + bitrev4(e)
    int kstar = ((e & 1) << 3) | (((e >> 1) & 1) << 2) | (((e >> 2) & 1) << 1) | ((e >> 3) & 1);
    int idx = d * 16 + kstar;
    float val = s[0];
    size_t o = (size_t)row * DD + idx;

    if (MODE != 2) nxtH[o] = __float2half_rn(val);
    if (MODE == 0) {
        const float* p = (row < NU) ? ue : ie2;
        float e0 = __builtin_nontemporal_load(&p[o]);
        __builtin_nontemporal_store(e0 + val, &acc[o]);
    } else if (MODE == 1) {
        float a = __builtin_nontemporal_load(&acc[o]);
        __builtin_nontemporal_store(a + val, &acc[o]);
    } else {
        float a = __builtin_nontemporal_load(&acc[o]);
        __builtin_nontemporal_store((a + val) * 0.25f, &acc[o]);
    }
}

// ---- launch -------------------------------------------------------------

extern "C" void kernel_launch(void* const* d_in, const int* in_sizes, int n_in,
                              void* d_out, int out_size, void* d_ws, size_t ws_size,
                              hipStream_t stream) {
    const float* ue   = (const float*)d_in[0];
    const float* ie   = (const float*)d_in[1];
    const int*   rows = (const int*)d_in[2];
    const int*   cols = (const int*)d_in[3];
    const float* vals = (const float*)d_in[4];
    float* acc = (float*)d_out;

    char* ws = (char*)d_ws;
    size_t p = 0;
    auto alloc = [&](size_t bytes) -> void* {
        p = (p + 255) & ~(size_t)255;
        void* r = ws + p;
        p += bytes;
        return r;
    };
    int2*  edges   = (int2*) alloc((size_t)NE * 8);         // 38.4 MB final CSR
    uint2* h0      = (uint2*)alloc((size_t)NN * 16 * 8);    // 38.4 MB fp16 table
    uint2* h1      = (uint2*)alloc((size_t)NN * 16 * 8);    // 38.4 MB fp16 table
    int*   bcnt    = (int*)  alloc((size_t)NB * 4);
    int*   bbase   = (int*)  alloc((size_t)(NB + 1) * 4);
    int*   gcursor = (int*)  alloc((size_t)NB * 4);
    int*   off     = (int*)  alloc((size_t)(NN + 1) * 4);
    // recs (38.4 MB) aliases h1: dead after fine_sort, h1 first written by spmm<0>
    int2*  recs = (int2*)h1;
    // h2 aliases h0: h0 dead after spmm<0> (spmm<1> gathers h1 only)
    uint2* h2 = h0;

    // 1. CSR build: hist -> scan -> LDS-staged coarse scatter -> fine sort
    hipMemsetAsync(bcnt, 0, (size_t)NB * 4, stream);
    bucket_hist   <<<(NE + CE_HIST - 1) / CE_HIST, 1024, 0, stream>>>(rows, bcnt);
    bucket_scan   <<<1, NB, 0, stream>>>(bcnt, bbase, gcursor);
    bucket_scatter<<<(NE + CE_SCAT - 1) / CE_SCAT, 1024, 0, stream>>>(rows, cols, vals, gcursor, recs);
    fine_sort     <<<NB, 1024, 0, stream>>>(bbase, recs, edges, off);

    // 2. E -> fp16 table (after fine_sort: recs aliases h1, not h0 — safe order)
    const float* ie2 = ie - (size_t)NU * DD;   // pre-shifted item base for concat view
    e_to_h<<<(NN * 16 + 255) / 256, 256, 0, stream>>>(
        (const float4*)ue, (const float4*)ie2 + (size_t)NU * 16, h0);

    // 3. three propagation layers; acc (= d_out) fused, final /4 fused into last
    const int spmm_blocks = NN / 4;   // 1 row/wave, 4 waves/block
    spmm16_kernel<0><<<spmm_blocks, 256, 0, stream>>>(off, edges, (const uint4*)h0, (__half*)h1, acc, ue, ie2);
    spmm16_kernel<1><<<spmm_blocks, 256, 0, stream>>>(off, edges, (const uint4*)h1, (__half*)h2, acc, ue, ie2);
    spmm16_kernel<2><<<spmm_blocks, 256, 0, stream>>>(off, edges, (const uint4*)h2, (__half*)h1, acc, ue, ie2);
}

// Round 3
// 668.713 us; speedup vs baseline: 1.0939x; 1.0035x over previous
//
#include <hip/hip_runtime.h>
#include <hip/hip_fp16.h>

// LightGCN on MI355X — bucket-sort CSR build + 16-edge-parallel SpMM, fp16 gathers.
// final = (E + A E + A^2 E + A^3 E) / 4,  E = concat(user_emb, item_emb)
//
// R8 changes vs R7 (spmm was VALU-issue-bound: VALUBusy 61%, HBM 40%, occ 76%):
//  - inner loop uses v_fma_mix_f32 (f32 += f16*f32, op_sel picks the half) via
//    inline asm: 16 ops/lane-iter replace 16 v_cvt_f32_f16 + 16 v_fmac_f32.
//    Inner-loop VALU ~45 -> ~29 per iter.
//  - everything else identical to R7.

#define NU 200000
#define NI 100000
#define NN 300000          // NU + NI
#define DD 64
#define NE 4800000
#define NB 512             // coarse buckets
#define RPB 586            // rows per bucket: 512*586 = 300032 >= NN
#define NRPAD 640          // RPB padded for fine_sort scan
#define CE_HIST 8192       // edges per block, bucket_hist  (586 blocks)
#define CE_SCAT 6144       // edges per block, bucket_scatter (782 blocks)
#define EPT (CE_SCAT / 1024)   // 6 edges per thread in scatter

// f32 acc += (lo/hi f16 of h32) * v32   — single VALU op, no separate cvt
#define FMA_MIX_LO(acc, h32, vv) \
    asm("v_fma_mix_f32 %0, %1, %2, %0 op_sel_hi:[1,0,0]" \
        : "+v"(acc) : "v"(h32), "v"(vv))
#define FMA_MIX_HI(acc, h32, vv) \
    asm("v_fma_mix_f32 %0, %1, %2, %0 op_sel:[1,0,0] op_sel_hi:[1,0,0]" \
        : "+v"(acc) : "v"(h32), "v"(vv))

// ---- Phase 1: bucket histogram (LDS pre-aggregated, int4 loads) ---------

__global__ void bucket_hist(const int* __restrict__ rows, int* __restrict__ bcnt) {
    __shared__ int h[NB];
    int tid = threadIdx.x;
    for (int i = tid; i < NB; i += 1024) h[i] = 0;
    __syncthreads();
    const int4* r4 = (const int4*)rows;
    int q0 = blockIdx.x * (CE_HIST / 4);
    for (int k = 0; k < CE_HIST / 4096; ++k) {
        int q = q0 + k * 1024 + tid;
        if (q < NE / 4) {
            int4 r = r4[q];
            atomicAdd(&h[(unsigned)r.x / RPB], 1);
            atomicAdd(&h[(unsigned)r.y / RPB], 1);
            atomicAdd(&h[(unsigned)r.z / RPB], 1);
            atomicAdd(&h[(unsigned)r.w / RPB], 1);
        }
    }
    __syncthreads();
    for (int i = tid; i < NB; i += 1024) {
        int c = h[i];
        if (c) atomicAdd(&bcnt[i], c);
    }
}

// ---- Phase 2a: exclusive scan of 512 bucket counts ----------------------

__global__ void bucket_scan(const int* __restrict__ bcnt, int* __restrict__ bbase,
                            int* __restrict__ gcursor) {
    __shared__ int sh[NB];
    int t = threadIdx.x;          // 512 threads
    int v = bcnt[t];
    sh[t] = v;
    __syncthreads();
    for (int o = 1; o < NB; o <<= 1) {
        int x = (t >= o) ? sh[t - o] : 0;
        __syncthreads();
        sh[t] += x;
        __syncthreads();
    }
    int excl = sh[t] - v;
    bbase[t] = excl;
    gcursor[t] = excl;
    if (t == NB - 1) bbase[NB] = NE;
}

// ---- Phase 2b: LDS-staged coarse sort, coalesced run writeback ----------
// record: x = (rowlocal << 19) | col   (rowlocal < 586 < 2^10, col < 2^19)
//         y = float bits of val

__global__ void bucket_scatter(const int* __restrict__ rows, const int* __restrict__ cols,
                               const float* __restrict__ vals,
                               int* __restrict__ gcursor, int2* __restrict__ recs) {
    __shared__ int  cnt[NB];        // hist, then reused as staging cursor
    __shared__ int  lofs[NB + 1];   // local exclusive scan (+ total sentinel)
    __shared__ int  dlt[NB];        // global_base - local_base per bucket
    __shared__ int2 stg[CE_SCAT];   // 48KB staging
    int tid = threadIdx.x;          // 1024 threads
    if (tid < NB) cnt[tid] = 0;
    __syncthreads();
    int e0 = blockIdx.x * CE_SCAT;
    int r[EPT];
    #pragma unroll
    for (int k = 0; k < EPT; ++k) {
        int e = e0 + k * 1024 + tid;
        r[k] = -1;
        if (e < NE) {
            r[k] = rows[e];
            atomicAdd(&cnt[(unsigned)r[k] / RPB], 1);
        }
    }
    __syncthreads();
    // inclusive scan of cnt into lofs (512 entries, first 512 threads)
    if (tid < NB) lofs[tid] = cnt[tid];
    __syncthreads();
    for (int o = 1; o < NB; o <<= 1) {
        int x = 0;
        if (tid < NB && tid >= o) x = lofs[tid - o];
        __syncthreads();
        if (tid < NB) lofs[tid] += x;
        __syncthreads();
    }
    // convert to exclusive, reserve global run, reset cursor
    if (tid < NB) {
        int incl = lofs[tid];
        int c = cnt[tid];
        int excl = incl - c;
        int gb = c ? atomicAdd(&gcursor[tid], c) : 0;
        lofs[tid] = excl;
        dlt[tid] = gb - excl;
        cnt[tid] = 0;
        if (tid == NB - 1) lofs[NB] = incl;   // total staged in this block
    }
    __syncthreads();
    // stage records bucket-sorted in LDS
    #pragma unroll
    for (int k = 0; k < EPT; ++k) {
        int e = e0 + k * 1024 + tid;
        if (e < NE) {
            int rr = r[k];
            int b = (unsigned)rr / RPB;
            int p = lofs[b] + atomicAdd(&cnt[b], 1);
            int rl = rr - b * RPB;
            stg[p] = make_int2((rl << 19) | cols[e], __float_as_int(vals[e]));
        }
    }
    __syncthreads();
    // coalesced writeback: consecutive i -> consecutive global pos within runs
    int total = lofs[NB];
    for (int i = tid; i < total; i += 1024) {
        int b = 0;
        #pragma unroll
        for (int s = NB >> 1; s > 0; s >>= 1)
            if (lofs[b + s] <= i) b += s;     // greatest b with lofs[b] <= i
        recs[dlt[b] + i] = stg[i];
    }
}

// ---- Phase 3: per-bucket LDS counting sort -> final CSR -----------------

__global__ void fine_sort(const int* __restrict__ bbase, const int2* __restrict__ recs,
                          int2* __restrict__ edges, int* __restrict__ off) {
    __shared__ int cnt[NRPAD];
    __shared__ int scn[NRPAD];
    __shared__ int cur[NRPAD];
    int b = blockIdx.x, tid = threadIdx.x;   // 1024 threads
    int e0 = bbase[b], e1 = bbase[b + 1];
    if (tid < NRPAD) cnt[tid] = 0;
    __syncthreads();
    for (int e = e0 + tid; e < e1; e += 1024)
        atomicAdd(&cnt[recs[e].x >> 19], 1);
    __syncthreads();
    int v = 0;
    if (tid < NRPAD) { v = cnt[tid]; scn[tid] = v; }
    __syncthreads();
    for (int o = 1; o < NRPAD; o <<= 1) {
        int x = 0;
        if (tid < NRPAD && tid >= o) x = scn[tid - o];
        __syncthreads();
        if (tid < NRPAD) scn[tid] += x;
        __syncthreads();
    }
    if (tid < NRPAD) {
        int excl = e0 + scn[tid] - v;
        cur[tid] = excl;
        if (tid < RPB) {
            int row = b * RPB + tid;
            if (row < NN) off[row] = excl;
        }
    }
    if (b == 0 && tid == 0) off[NN] = NE;
    __syncthreads();
    for (int e = e0 + tid; e < e1; e += 1024) {
        int2 rc = recs[e];
        int rl = rc.x >> 19;
        int p = atomicAdd(&cur[rl], 1);
        edges[p] = make_int2(rc.x & 0x7FFFF, rc.y);   // (col, val-bits)
    }
}

// ---- E (fp32 concat view) -> h0 (fp16, [NN][64]) ------------------------

__global__ void e_to_h(const float4* __restrict__ ue4, const float4* __restrict__ ie4,
                       uint2* __restrict__ h) {
    int i = blockIdx.x * blockDim.x + threadIdx.x;   // over NN*16 float4-groups
    if (i >= NN * 16) return;
    float4 v = (i < NU * 16) ? ue4[i] : ie4[i - NU * 16];
    __half2 a = __float22half2_rn(make_float2(v.x, v.y));
    __half2 b = __float22half2_rn(make_float2(v.z, v.w));
    h[i] = make_uint2(*(unsigned*)&a, *(unsigned*)&b);
}

// ---- SpMM: 1 row/wave; lane = (e = lane>>2 edge slot, d = lane&3 dims) ----
// 16 edges gathered in parallel per step; each edge's 128B fp16 row read by
// 4 lanes x 2 dwordx4. Inner accumulate via v_fma_mix_f32 (f16 consumed in
// place). Reduce over edge slots via recursive-halving reduce-scatter (15
// shuffles); afterwards lane e*4+d holds output element d*16 + bitrev4(e).
// MODE 0: acc = E32[row] + sum;  1: acc += sum;  2: acc = (acc+sum)*0.25.

template <int MODE>
__global__ void spmm16_kernel(const int* __restrict__ off, const int2* __restrict__ edges,
                              const uint4* __restrict__ h8,   // fp16 table, [NN][8] x 16B
                              __half* __restrict__ nxtH,      // fp16 output, elementwise
                              float* __restrict__ acc,
                              const float* __restrict__ ue, const float* __restrict__ ie2) {
    int row  = (blockIdx.x * blockDim.x + threadIdx.x) >> 6;  // one row per wave
    int lane = threadIdx.x & 63;
    int e    = lane >> 2;     // edge slot 0..15
    int d    = lane & 3;      // dim quarter (16 halves = 32B)
    if (row >= NN) return;

    int start = off[row], end = off[row + 1];

    float s[16];
    #pragma unroll
    for (int k = 0; k < 16; ++k) s[k] = 0.f;

    for (int base = start; base < end; base += 16) {
        int ei = base + e;
        if (ei < end) {
            long long evl = __builtin_nontemporal_load((const long long*)&edges[ei]);
            int   c = (int)(unsigned)evl;
            float v = __int_as_float((int)(evl >> 32));
            const uint4* hp = &h8[(size_t)c * 8 + d * 2];
            uint4 ha = hp[0];              // halves d*16 + 0..7
            uint4 hb = hp[1];              // halves d*16 + 8..15
            FMA_MIX_LO(s[0],  ha.x, v); FMA_MIX_HI(s[1],  ha.x, v);
            FMA_MIX_LO(s[2],  ha.y, v); FMA_MIX_HI(s[3],  ha.y, v);
            FMA_MIX_LO(s[4],  ha.z, v); FMA_MIX_HI(s[5],  ha.z, v);
            FMA_MIX_LO(s[6],  ha.w, v); FMA_MIX_HI(s[7],  ha.w, v);
            FMA_MIX_LO(s[8],  hb.x, v); FMA_MIX_HI(s[9],  hb.x, v);
            FMA_MIX_LO(s[10], hb.y, v); FMA_MIX_HI(s[11], hb.y, v);
            FMA_MIX_LO(s[12], hb.z, v); FMA_MIX_HI(s[13], hb.z, v);
            FMA_MIX_LO(s[14], hb.w, v); FMA_MIX_HI(s[15], hb.w, v);
        }
    }

    // recursive-halving reduce-scatter over the 16 edge slots (lane bits 2..5).
    // At each step, lanes with the bit set keep the upper half of their range.
    {
        bool up = (lane & 4) != 0;
        #pragma unroll
        for (int k = 0; k < 8; ++k) {
            float keep = up ? s[k + 8] : s[k];
            float give = up ? s[k] : s[k + 8];
            s[k] = keep + __shfl_xor(give, 4);
        }
    }
    {
        bool up = (lane & 8) != 0;
        #pragma unroll
        for (int k = 0; k < 4; ++k) {
            float keep = up ? s[k + 4] : s[k];
            float give = up ? s[k] : s[k + 4];
            s[k] = keep + __shfl_xor(give, 8);
        }
    }
    {
        bool up = (lane & 16) != 0;
        #pragma unroll
        for (int k = 0; k < 2; ++k) {
            float keep = up ? s[k + 2] : s[k];
            float give = up ? s[k] : s[k + 2];
            s[k] = keep + __shfl_xor(give, 16);
        }
    }
    {
        bool up = (lane & 32) != 0;
        float keep = up ? s[1] : s[0];
        float give = up ? s[0] : s[1];
        s[0] = keep + __shfl_xor(give, 32);
    }

    // lane e*4+d now holds element d*16 + bitrev4(e)
    int kstar = ((e & 1) << 3) | (((e >> 1) & 1) << 2) | (((e >> 2) & 1) << 1) | ((e >> 3) & 1);
    int idx = d * 16 + kstar;
    float val = s[0];
    size_t o = (size_t)row * DD + idx;

    if (MODE != 2) nxtH[o] = __float2half_rn(val);
    if (MODE == 0) {
        const float* p = (row < NU) ? ue : ie2;
        float e0 = __builtin_nontemporal_load(&p[o]);
        __builtin_nontemporal_store(e0 + val, &acc[o]);
    } else if (MODE == 1) {
        float a = __builtin_nontemporal_load(&acc[o]);
        __builtin_nontemporal_store(a + val, &acc[o]);
    } else {
        float a = __builtin_nontemporal_load(&acc[o]);
        __builtin_nontemporal_store((a + val) * 0.25f, &acc[o]);
    }
}

// ---- launch -------------------------------------------------------------

extern "C" void kernel_launch(void* const* d_in, const int* in_sizes, int n_in,
                              void* d_out, int out_size, void* d_ws, size_t ws_size,
                              hipStream_t stream) {
    const float* ue   = (const float*)d_in[0];
    const float* ie   = (const float*)d_in[1];
    const int*   rows = (const int*)d_in[2];
    const int*   cols = (const int*)d_in[3];
    const float* vals = (const float*)d_in[4];
    float* acc = (float*)d_out;

    char* ws = (char*)d_ws;
    size_t p = 0;
    auto alloc = [&](size_t bytes) -> void* {
        p = (p + 255) & ~(size_t)255;
        void* r = ws + p;
        p += bytes;
        return r;
    };
    int2*  edges   = (int2*) alloc((size_t)NE * 8);         // 38.4 MB final CSR
    uint2* h0      = (uint2*)alloc((size_t)NN * 16 * 8);    // 38.4 MB fp16 table
    uint2* h1      = (uint2*)alloc((size_t)NN * 16 * 8);    // 38.4 MB fp16 table
    int*   bcnt    = (int*)  alloc((size_t)NB * 4);
    int*   bbase   = (int*)  alloc((size_t)(NB + 1) * 4);
    int*   gcursor = (int*)  alloc((size_t)NB * 4);
    int*   off     = (int*)  alloc((size_t)(NN + 1) * 4);
    // recs (38.4 MB) aliases h1: dead after fine_sort, h1 first written by spmm<0>
    int2*  recs = (int2*)h1;
    // h2 aliases h0: h0 dead after spmm<0> (spmm<1> gathers h1 only)
    uint2* h2 = h0;

    // 1. CSR build: hist -> scan -> LDS-staged coarse scatter -> fine sort
    hipMemsetAsync(bcnt, 0, (size_t)NB * 4, stream);
    bucket_hist   <<<(NE + CE_HIST - 1) / CE_HIST, 1024, 0, stream>>>(rows, bcnt);
    bucket_scan   <<<1, NB, 0, stream>>>(bcnt, bbase, gcursor);
    bucket_scatter<<<(NE + CE_SCAT - 1) / CE_SCAT, 1024, 0, stream>>>(rows, cols, vals, gcursor, recs);
    fine_sort     <<<NB, 1024, 0, stream>>>(bbase, recs, edges, off);

    // 2. E -> fp16 table (after fine_sort: recs aliases h1, not h0 — safe order)
    const float* ie2 = ie - (size_t)NU * DD;   // pre-shifted item base for concat view
    e_to_h<<<(NN * 16 + 255) / 256, 256, 0, stream>>>(
        (const float4*)ue, (const float4*)ie2 + (size_t)NU * 16, h0);

    // 3. three propagation layers; acc (= d_out) fused, final /4 fused into last
    const int spmm_blocks = NN / 4;   // 1 row/wave, 4 waves/block
    spmm16_kernel<0><<<spmm_blocks, 256, 0, stream>>>(off, edges, (const uint4*)h0, (__half*)h1, acc, ue, ie2);
    spmm16_kernel<1><<<spmm_blocks, 256, 0, stream>>>(off, edges, (const uint4*)h1, (__half*)h2, acc, ue, ie2);
    spmm16_kernel<2><<<spmm_blocks, 256, 0, stream>>>(off, edges, (const uint4*)h2, (__half*)h1, acc, ue, ie2);
}

// Round 4
// 606.952 us; speedup vs baseline: 1.2052x; 1.1018x over previous
//
#include <hip/hip_runtime.h>
#include <hip/hip_fp16.h>

// LightGCN on MI355X — bucket-sort CSR build + 2-row/wave SpMM, fp16 gathers.
// final = (E + A E + A^2 E + A^3 E) / 4,  E = concat(user_emb, item_emb)
//
// R9 changes vs R8 (post-mortem: NOT VALU-bound — fma_mix cut VALU ~1/3, time
// moved 0.6%. Latency-chain-bound: off->edge->gather->4xshuffle->acc-load tail):
//  - spmm2r: 2 rows per wave (half-wave each, e8 x d4). Two independent
//    memory chains per wave = 2x outstanding requests at equal occupancy.
//  - epilogue acc/E operand prefetched at wave start (addr depends only on
//    row) -> its ~500cy latency overlaps the gather loop.
//  - reduce: 3 dependent shuffle stages (was 4); lane ends with a CONSECUTIVE
//    element pair -> float2/half2 epilogue.
//  - next edge-chunk preloaded before current chunk's gather+FMA.
//  - bucket_hist: CE_HIST 8192 -> 32768 (147 blocks, amortized LDS zero/flush).

#define NU 200000
#define NI 100000
#define NN 300000          // NU + NI
#define DD 64
#define NE 4800000
#define NB 512             // coarse buckets
#define RPB 586            // rows per bucket: 512*586 = 300032 >= NN
#define NRPAD 640          // RPB padded for fine_sort scan
#define CE_HIST 32768      // edges per block, bucket_hist  (147 blocks)
#define CE_SCAT 6144       // edges per block, bucket_scatter (782 blocks)
#define EPT (CE_SCAT / 1024)   // 6 edges per thread in scatter

// f32 acc += (lo/hi f16 of h32) * v32   — single VALU op, no separate cvt
#define FMA_MIX_LO(acc, h32, vv) \
    asm("v_fma_mix_f32 %0, %1, %2, %0 op_sel_hi:[1,0,0]" \
        : "+v"(acc) : "v"(h32), "v"(vv))
#define FMA_MIX_HI(acc, h32, vv) \
    asm("v_fma_mix_f32 %0, %1, %2, %0 op_sel:[1,0,0] op_sel_hi:[1,0,0]" \
        : "+v"(acc) : "v"(h32), "v"(vv))

// ---- Phase 1: bucket histogram (LDS pre-aggregated, int4 loads) ---------

__global__ void bucket_hist(const int* __restrict__ rows, int* __restrict__ bcnt) {
    __shared__ int h[NB];
    int tid = threadIdx.x;
    for (int i = tid; i < NB; i += 1024) h[i] = 0;
    __syncthreads();
    const int4* r4 = (const int4*)rows;
    int q0 = blockIdx.x * (CE_HIST / 4);
    for (int k = 0; k < CE_HIST / 4096; ++k) {
        int q = q0 + k * 1024 + tid;
        if (q < NE / 4) {
            int4 r = r4[q];
            atomicAdd(&h[(unsigned)r.x / RPB], 1);
            atomicAdd(&h[(unsigned)r.y / RPB], 1);
            atomicAdd(&h[(unsigned)r.z / RPB], 1);
            atomicAdd(&h[(unsigned)r.w / RPB], 1);
        }
    }
    __syncthreads();
    for (int i = tid; i < NB; i += 1024) {
        int c = h[i];
        if (c) atomicAdd(&bcnt[i], c);
    }
}

// ---- Phase 2a: exclusive scan of 512 bucket counts ----------------------

__global__ void bucket_scan(const int* __restrict__ bcnt, int* __restrict__ bbase,
                            int* __restrict__ gcursor) {
    __shared__ int sh[NB];
    int t = threadIdx.x;          // 512 threads
    int v = bcnt[t];
    sh[t] = v;
    __syncthreads();
    for (int o = 1; o < NB; o <<= 1) {
        int x = (t >= o) ? sh[t - o] : 0;
        __syncthreads();
        sh[t] += x;
        __syncthreads();
    }
    int excl = sh[t] - v;
    bbase[t] = excl;
    gcursor[t] = excl;
    if (t == NB - 1) bbase[NB] = NE;
}

// ---- Phase 2b: LDS-staged coarse sort, coalesced run writeback ----------
// record: x = (rowlocal << 19) | col   (rowlocal < 586 < 2^10, col < 2^19)
//         y = float bits of val

__global__ void bucket_scatter(const int* __restrict__ rows, const int* __restrict__ cols,
                               const float* __restrict__ vals,
                               int* __restrict__ gcursor, int2* __restrict__ recs) {
    __shared__ int  cnt[NB];        // hist, then reused as staging cursor
    __shared__ int  lofs[NB + 1];   // local exclusive scan (+ total sentinel)
    __shared__ int  dlt[NB];        // global_base - local_base per bucket
    __shared__ int2 stg[CE_SCAT];   // 48KB staging
    int tid = threadIdx.x;          // 1024 threads
    if (tid < NB) cnt[tid] = 0;
    __syncthreads();
    int e0 = blockIdx.x * CE_SCAT;
    int r[EPT];
    #pragma unroll
    for (int k = 0; k < EPT; ++k) {
        int e = e0 + k * 1024 + tid;
        r[k] = -1;
        if (e < NE) {
            r[k] = rows[e];
            atomicAdd(&cnt[(unsigned)r[k] / RPB], 1);
        }
    }
    __syncthreads();
    // inclusive scan of cnt into lofs (512 entries, first 512 threads)
    if (tid < NB) lofs[tid] = cnt[tid];
    __syncthreads();
    for (int o = 1; o < NB; o <<= 1) {
        int x = 0;
        if (tid < NB && tid >= o) x = lofs[tid - o];
        __syncthreads();
        if (tid < NB) lofs[tid] += x;
        __syncthreads();
    }
    // convert to exclusive, reserve global run, reset cursor
    if (tid < NB) {
        int incl = lofs[tid];
        int c = cnt[tid];
        int excl = incl - c;
        int gb = c ? atomicAdd(&gcursor[tid], c) : 0;
        lofs[tid] = excl;
        dlt[tid] = gb - excl;
        cnt[tid] = 0;
        if (tid == NB - 1) lofs[NB] = incl;   // total staged in this block
    }
    __syncthreads();
    // stage records bucket-sorted in LDS
    #pragma unroll
    for (int k = 0; k < EPT; ++k) {
        int e = e0 + k * 1024 + tid;
        if (e < NE) {
            int rr = r[k];
            int b = (unsigned)rr / RPB;
            int p = lofs[b] + atomicAdd(&cnt[b], 1);
            int rl = rr - b * RPB;
            stg[p] = make_int2((rl << 19) | cols[e], __float_as_int(vals[e]));
        }
    }
    __syncthreads();
    // coalesced writeback: consecutive i -> consecutive global pos within runs
    int total = lofs[NB];
    for (int i = tid; i < total; i += 1024) {
        int b = 0;
        #pragma unroll
        for (int s = NB >> 1; s > 0; s >>= 1)
            if (lofs[b + s] <= i) b += s;     // greatest b with lofs[b] <= i
        recs[dlt[b] + i] = stg[i];
    }
}

// ---- Phase 3: per-bucket LDS counting sort -> final CSR -----------------

__global__ void fine_sort(const int* __restrict__ bbase, const int2* __restrict__ recs,
                          int2* __restrict__ edges, int* __restrict__ off) {
    __shared__ int cnt[NRPAD];
    __shared__ int scn[NRPAD];
    __shared__ int cur[NRPAD];
    int b = blockIdx.x, tid = threadIdx.x;   // 1024 threads
    int e0 = bbase[b], e1 = bbase[b + 1];
    if (tid < NRPAD) cnt[tid] = 0;
    __syncthreads();
    for (int e = e0 + tid; e < e1; e += 1024)
        atomicAdd(&cnt[recs[e].x >> 19], 1);
    __syncthreads();
    int v = 0;
    if (tid < NRPAD) { v = cnt[tid]; scn[tid] = v; }
    __syncthreads();
    for (int o = 1; o < NRPAD; o <<= 1) {
        int x = 0;
        if (tid < NRPAD && tid >= o) x = scn[tid - o];
        __syncthreads();
        if (tid < NRPAD) scn[tid] += x;
        __syncthreads();
    }
    if (tid < NRPAD) {
        int excl = e0 + scn[tid] - v;
        cur[tid] = excl;
        if (tid < RPB) {
            int row = b * RPB + tid;
            if (row < NN) off[row] = excl;
        }
    }
    if (b == 0 && tid == 0) off[NN] = NE;
    __syncthreads();
    for (int e = e0 + tid; e < e1; e += 1024) {
        int2 rc = recs[e];
        int rl = rc.x >> 19;
        int p = atomicAdd(&cur[rl], 1);
        edges[p] = make_int2(rc.x & 0x7FFFF, rc.y);   // (col, val-bits)
    }
}

// ---- E (fp32 concat view) -> h0 (fp16, [NN][64]) ------------------------

__global__ void e_to_h(const float4* __restrict__ ue4, const float4* __restrict__ ie4,
                       uint2* __restrict__ h) {
    int i = blockIdx.x * blockDim.x + threadIdx.x;   // over NN*16 float4-groups
    if (i >= NN * 16) return;
    float4 v = (i < NU * 16) ? ue4[i] : ie4[i - NU * 16];
    __half2 a = __float22half2_rn(make_float2(v.x, v.y));
    __half2 b = __float22half2_rn(make_float2(v.z, v.w));
    h[i] = make_uint2(*(unsigned*)&a, *(unsigned*)&b);
}

// ---- SpMM: 2 rows/wave; half-wave per row, l = lane&31 = (e<<2)|d --------
// e = l>>2 (8 edge slots), d = l&3 (32B dim quarter). Per iteration each row
// gathers 8 edges (16 total in flight per wave). Reduce over e = 3 recursive-
// halving shuffle stages; lane ends owning the consecutive element pair
// idx = d*16 + rev3(e)*2 + {0,1}. Epilogue operand (acc or E) prefetched at
// wave start; next edge chunk preloaded before current chunk's gather.
// MODE 0: acc = E32[row] + sum;  1: acc += sum;  2: acc = (acc+sum)*0.25.

template <int MODE>
__global__ void spmm2r_kernel(const int* __restrict__ off, const int2* __restrict__ edges,
                              const uint4* __restrict__ h8,   // fp16 table, [NN][8] x 16B
                              __half* __restrict__ nxtH,      // fp16 output
                              float* __restrict__ acc,
                              const float* __restrict__ ue, const float* __restrict__ ie2) {
    int wave = (blockIdx.x * blockDim.x + threadIdx.x) >> 6;
    int lane = threadIdx.x & 63;
    int l    = lane & 31;         // index within half-wave
    int e    = l >> 2;            // edge slot 0..7
    int d    = l & 3;             // dim quarter (16 halves = 32B)
    int row  = wave * 2 + (lane >> 5);   // NN even: no guard needed

    int start = off[row], end = off[row + 1];

    // final consecutive element pair owned by this lane
    int idx = d * 16 + (((l >> 2) & 1) << 3) + (((l >> 3) & 1) << 2) + (((l >> 4) & 1) << 1);
    size_t o = (size_t)row * DD + idx;

    // prefetch epilogue operand (address depends only on row/lane)
    float b0, b1;
    if (MODE == 0) {
        const float* p = (row < NU) ? ue : ie2;
        b0 = __builtin_nontemporal_load(&p[o]);
        b1 = __builtin_nontemporal_load(&p[o + 1]);
    } else {
        b0 = __builtin_nontemporal_load(&acc[o]);
        b1 = __builtin_nontemporal_load(&acc[o + 1]);
    }

    float s[16];
    #pragma unroll
    for (int k = 0; k < 16; ++k) s[k] = 0.f;

    // preloaded edge record for the current chunk
    int ec = 0; float vc = 0.f;
    {
        int ei = start + e;
        if (ei < end) {
            long long evl = __builtin_nontemporal_load((const long long*)&edges[ei]);
            ec = (int)(unsigned)evl;
            vc = __int_as_float((int)(evl >> 32));
        }
    }
    for (int base = start; base < end; base += 8) {
        // preload next chunk's edge record (overlaps current gather+FMA)
        int en = 0; float vn = 0.f;
        {
            int ein = base + 8 + e;
            if (ein < end) {
                long long evl = __builtin_nontemporal_load((const long long*)&edges[ein]);
                en = (int)(unsigned)evl;
                vn = __int_as_float((int)(evl >> 32));
            }
        }
        if (base + e < end) {
            const uint4* hp = &h8[(size_t)(unsigned)ec * 8 + d * 2];
            uint4 ha = hp[0];              // halves d*32 + 0..7   (bytes d*32..)
            uint4 hb = hp[1];              // halves d*32 + 8..15
            FMA_MIX_LO(s[0],  ha.x, vc); FMA_MIX_HI(s[1],  ha.x, vc);
            FMA_MIX_LO(s[2],  ha.y, vc); FMA_MIX_HI(s[3],  ha.y, vc);
            FMA_MIX_LO(s[4],  ha.z, vc); FMA_MIX_HI(s[5],  ha.z, vc);
            FMA_MIX_LO(s[6],  ha.w, vc); FMA_MIX_HI(s[7],  ha.w, vc);
            FMA_MIX_LO(s[8],  hb.x, vc); FMA_MIX_HI(s[9],  hb.x, vc);
            FMA_MIX_LO(s[10], hb.y, vc); FMA_MIX_HI(s[11], hb.y, vc);
            FMA_MIX_LO(s[12], hb.z, vc); FMA_MIX_HI(s[13], hb.z, vc);
            FMA_MIX_LO(s[14], hb.w, vc); FMA_MIX_HI(s[15], hb.w, vc);
        }
        ec = en; vc = vn;
    }

    // recursive-halving reduce-scatter over the 8 edge slots (lane bits 2..4)
    {
        bool up = (l & 4) != 0;
        #pragma unroll
        for (int k = 0; k < 8; ++k) {
            float keep = up ? s[k + 8] : s[k];
            float give = up ? s[k] : s[k + 8];
            s[k] = keep + __shfl_xor(give, 4);
        }
    }
    {
        bool up = (l & 8) != 0;
        #pragma unroll
        for (int k = 0; k < 4; ++k) {
            float keep = up ? s[k + 4] : s[k];
            float give = up ? s[k] : s[k + 4];
            s[k] = keep + __shfl_xor(give, 8);
        }
    }
    {
        bool up = (l & 16) != 0;
        #pragma unroll
        for (int k = 0; k < 2; ++k) {
            float keep = up ? s[k + 2] : s[k];
            float give = up ? s[k] : s[k + 2];
            s[k] = keep + __shfl_xor(give, 16);
        }
    }
    // lane now owns elements idx, idx+1 with values s[0], s[1]

    if (MODE != 2) {
        __half2 hh = __float22half2_rn(make_float2(s[0], s[1]));
        *(__half2*)&nxtH[o] = hh;
    }
    float r0 = b0 + s[0], r1 = b1 + s[1];
    if (MODE == 2) { r0 *= 0.25f; r1 *= 0.25f; }
    __builtin_nontemporal_store(r0, &acc[o]);
    __builtin_nontemporal_store(r1, &acc[o + 1]);
}

// ---- launch -------------------------------------------------------------

extern "C" void kernel_launch(void* const* d_in, const int* in_sizes, int n_in,
                              void* d_out, int out_size, void* d_ws, size_t ws_size,
                              hipStream_t stream) {
    const float* ue   = (const float*)d_in[0];
    const float* ie   = (const float*)d_in[1];
    const int*   rows = (const int*)d_in[2];
    const int*   cols = (const int*)d_in[3];
    const float* vals = (const float*)d_in[4];
    float* acc = (float*)d_out;

    char* ws = (char*)d_ws;
    size_t p = 0;
    auto alloc = [&](size_t bytes) -> void* {
        p = (p + 255) & ~(size_t)255;
        void* r = ws + p;
        p += bytes;
        return r;
    };
    int2*  edges   = (int2*) alloc((size_t)NE * 8);         // 38.4 MB final CSR
    uint2* h0      = (uint2*)alloc((size_t)NN * 16 * 8);    // 38.4 MB fp16 table
    uint2* h1      = (uint2*)alloc((size_t)NN * 16 * 8);    // 38.4 MB fp16 table
    int*   bcnt    = (int*)  alloc((size_t)NB * 4);
    int*   bbase   = (int*)  alloc((size_t)(NB + 1) * 4);
    int*   gcursor = (int*)  alloc((size_t)NB * 4);
    int*   off     = (int*)  alloc((size_t)(NN + 1) * 4);
    // recs (38.4 MB) aliases h1: dead after fine_sort, h1 first written by spmm<0>
    int2*  recs = (int2*)h1;
    // h2 aliases h0: h0 dead after spmm<0> (spmm<1> gathers h1 only)
    uint2* h2 = h0;

    // 1. CSR build: hist -> scan -> LDS-staged coarse scatter -> fine sort
    hipMemsetAsync(bcnt, 0, (size_t)NB * 4, stream);
    bucket_hist   <<<(NE + CE_HIST - 1) / CE_HIST, 1024, 0, stream>>>(rows, bcnt);
    bucket_scan   <<<1, NB, 0, stream>>>(bcnt, bbase, gcursor);
    bucket_scatter<<<(NE + CE_SCAT - 1) / CE_SCAT, 1024, 0, stream>>>(rows, cols, vals, gcursor, recs);
    fine_sort     <<<NB, 1024, 0, stream>>>(bbase, recs, edges, off);

    // 2. E -> fp16 table (after fine_sort: recs aliases h1, not h0 — safe order)
    const float* ie2 = ie - (size_t)NU * DD;   // pre-shifted item base for concat view
    e_to_h<<<(NN * 16 + 255) / 256, 256, 0, stream>>>(
        (const float4*)ue, (const float4*)ie2 + (size_t)NU * 16, h0);

    // 3. three propagation layers; acc (= d_out) fused, final /4 fused into last
    const int spmm_blocks = NN / 8;   // 2 rows/wave, 4 waves/block
    spmm2r_kernel<0><<<spmm_blocks, 256, 0, stream>>>(off, edges, (const uint4*)h0, (__half*)h1, acc, ue, ie2);
    spmm2r_kernel<1><<<spmm_blocks, 256, 0, stream>>>(off, edges, (const uint4*)h1, (__half*)h2, acc, ue, ie2);
    spmm2r_kernel<2><<<spmm_blocks, 256, 0, stream>>>(off, edges, (const uint4*)h2, (__half*)h1, acc, ue, ie2);
}

// Round 5
// 595.101 us; speedup vs baseline: 1.2292x; 1.0199x over previous
//
#include <hip/hip_runtime.h>
#include <hip/hip_fp16.h>

// LightGCN on MI355X — bucket-sort CSR build + 2-row/wave 16-edge SpMM, fp16 gathers.
// final = (E + A E + A^2 E + A^3 E) / 4,  E = concat(user_emb, item_emb)
//
// R10 changes vs R9 (post-mortem: latency-chain theory CONFIRMED, 145->124.5;
// still latency-bound at 48% HBM / ~30% real VALU / 75% occ):
//  - spmm: 16 edges per iteration (2 per (e,d) lane slot, both FMA into the
//    SAME 16 accumulators). Doubles gathers in flight (2KB -> 4KB/wave);
//    Poisson(16)-degree row now completes in ONE serialized
//    edge-load -> gather -> FMA round (was ~1.6 on average).
//  - branchless tail: edge index clamped to end-1, v zeroed for ghost slots;
//    all loads issue unconditionally (no exec-mask churn); duplicate tail
//    gathers are L2 hits.
//  - everything else identical to R9.

#define NU 200000
#define NI 100000
#define NN 300000          // NU + NI
#define DD 64
#define NE 4800000
#define NB 512             // coarse buckets
#define RPB 586            // rows per bucket: 512*586 = 300032 >= NN
#define NRPAD 640          // RPB padded for fine_sort scan
#define CE_HIST 32768      // edges per block, bucket_hist  (147 blocks)
#define CE_SCAT 6144       // edges per block, bucket_scatter (782 blocks)
#define EPT (CE_SCAT / 1024)   // 6 edges per thread in scatter

// f32 acc += (lo/hi f16 of h32) * v32   — single VALU op, no separate cvt
#define FMA_MIX_LO(acc, h32, vv) \
    asm("v_fma_mix_f32 %0, %1, %2, %0 op_sel_hi:[1,0,0]" \
        : "+v"(acc) : "v"(h32), "v"(vv))
#define FMA_MIX_HI(acc, h32, vv) \
    asm("v_fma_mix_f32 %0, %1, %2, %0 op_sel:[1,0,0] op_sel_hi:[1,0,0]" \
        : "+v"(acc) : "v"(h32), "v"(vv))

// ---- Phase 1: bucket histogram (LDS pre-aggregated, int4 loads) ---------

__global__ void bucket_hist(const int* __restrict__ rows, int* __restrict__ bcnt) {
    __shared__ int h[NB];
    int tid = threadIdx.x;
    for (int i = tid; i < NB; i += 1024) h[i] = 0;
    __syncthreads();
    const int4* r4 = (const int4*)rows;
    int q0 = blockIdx.x * (CE_HIST / 4);
    for (int k = 0; k < CE_HIST / 4096; ++k) {
        int q = q0 + k * 1024 + tid;
        if (q < NE / 4) {
            int4 r = r4[q];
            atomicAdd(&h[(unsigned)r.x / RPB], 1);
            atomicAdd(&h[(unsigned)r.y / RPB], 1);
            atomicAdd(&h[(unsigned)r.z / RPB], 1);
            atomicAdd(&h[(unsigned)r.w / RPB], 1);
        }
    }
    __syncthreads();
    for (int i = tid; i < NB; i += 1024) {
        int c = h[i];
        if (c) atomicAdd(&bcnt[i], c);
    }
}

// ---- Phase 2a: exclusive scan of 512 bucket counts ----------------------

__global__ void bucket_scan(const int* __restrict__ bcnt, int* __restrict__ bbase,
                            int* __restrict__ gcursor) {
    __shared__ int sh[NB];
    int t = threadIdx.x;          // 512 threads
    int v = bcnt[t];
    sh[t] = v;
    __syncthreads();
    for (int o = 1; o < NB; o <<= 1) {
        int x = (t >= o) ? sh[t - o] : 0;
        __syncthreads();
        sh[t] += x;
        __syncthreads();
    }
    int excl = sh[t] - v;
    bbase[t] = excl;
    gcursor[t] = excl;
    if (t == NB - 1) bbase[NB] = NE;
}

// ---- Phase 2b: LDS-staged coarse sort, coalesced run writeback ----------
// record: x = (rowlocal << 19) | col   (rowlocal < 586 < 2^10, col < 2^19)
//         y = float bits of val

__global__ void bucket_scatter(const int* __restrict__ rows, const int* __restrict__ cols,
                               const float* __restrict__ vals,
                               int* __restrict__ gcursor, int2* __restrict__ recs) {
    __shared__ int  cnt[NB];        // hist, then reused as staging cursor
    __shared__ int  lofs[NB + 1];   // local exclusive scan (+ total sentinel)
    __shared__ int  dlt[NB];        // global_base - local_base per bucket
    __shared__ int2 stg[CE_SCAT];   // 48KB staging
    int tid = threadIdx.x;          // 1024 threads
    if (tid < NB) cnt[tid] = 0;
    __syncthreads();
    int e0 = blockIdx.x * CE_SCAT;
    int r[EPT];
    #pragma unroll
    for (int k = 0; k < EPT; ++k) {
        int e = e0 + k * 1024 + tid;
        r[k] = -1;
        if (e < NE) {
            r[k] = rows[e];
            atomicAdd(&cnt[(unsigned)r[k] / RPB], 1);
        }
    }
    __syncthreads();
    // inclusive scan of cnt into lofs (512 entries, first 512 threads)
    if (tid < NB) lofs[tid] = cnt[tid];
    __syncthreads();
    for (int o = 1; o < NB; o <<= 1) {
        int x = 0;
        if (tid < NB && tid >= o) x = lofs[tid - o];
        __syncthreads();
        if (tid < NB) lofs[tid] += x;
        __syncthreads();
    }
    // convert to exclusive, reserve global run, reset cursor
    if (tid < NB) {
        int incl = lofs[tid];
        int c = cnt[tid];
        int excl = incl - c;
        int gb = c ? atomicAdd(&gcursor[tid], c) : 0;
        lofs[tid] = excl;
        dlt[tid] = gb - excl;
        cnt[tid] = 0;
        if (tid == NB - 1) lofs[NB] = incl;   // total staged in this block
    }
    __syncthreads();
    // stage records bucket-sorted in LDS
    #pragma unroll
    for (int k = 0; k < EPT; ++k) {
        int e = e0 + k * 1024 + tid;
        if (e < NE) {
            int rr = r[k];
            int b = (unsigned)rr / RPB;
            int p = lofs[b] + atomicAdd(&cnt[b], 1);
            int rl = rr - b * RPB;
            stg[p] = make_int2((rl << 19) | cols[e], __float_as_int(vals[e]));
        }
    }
    __syncthreads();
    // coalesced writeback: consecutive i -> consecutive global pos within runs
    int total = lofs[NB];
    for (int i = tid; i < total; i += 1024) {
        int b = 0;
        #pragma unroll
        for (int s = NB >> 1; s > 0; s >>= 1)
            if (lofs[b + s] <= i) b += s;     // greatest b with lofs[b] <= i
        recs[dlt[b] + i] = stg[i];
    }
}

// ---- Phase 3: per-bucket LDS counting sort -> final CSR -----------------

__global__ void fine_sort(const int* __restrict__ bbase, const int2* __restrict__ recs,
                          int2* __restrict__ edges, int* __restrict__ off) {
    __shared__ int cnt[NRPAD];
    __shared__ int scn[NRPAD];
    __shared__ int cur[NRPAD];
    int b = blockIdx.x, tid = threadIdx.x;   // 1024 threads
    int e0 = bbase[b], e1 = bbase[b + 1];
    if (tid < NRPAD) cnt[tid] = 0;
    __syncthreads();
    for (int e = e0 + tid; e < e1; e += 1024)
        atomicAdd(&cnt[recs[e].x >> 19], 1);
    __syncthreads();
    int v = 0;
    if (tid < NRPAD) { v = cnt[tid]; scn[tid] = v; }
    __syncthreads();
    for (int o = 1; o < NRPAD; o <<= 1) {
        int x = 0;
        if (tid < NRPAD && tid >= o) x = scn[tid - o];
        __syncthreads();
        if (tid < NRPAD) scn[tid] += x;
        __syncthreads();
    }
    if (tid < NRPAD) {
        int excl = e0 + scn[tid] - v;
        cur[tid] = excl;
        if (tid < RPB) {
            int row = b * RPB + tid;
            if (row < NN) off[row] = excl;
        }
    }
    if (b == 0 && tid == 0) off[NN] = NE;
    __syncthreads();
    for (int e = e0 + tid; e < e1; e += 1024) {
        int2 rc = recs[e];
        int rl = rc.x >> 19;
        int p = atomicAdd(&cur[rl], 1);
        edges[p] = make_int2(rc.x & 0x7FFFF, rc.y);   // (col, val-bits)
    }
}

// ---- E (fp32 concat view) -> h0 (fp16, [NN][64]) ------------------------

__global__ void e_to_h(const float4* __restrict__ ue4, const float4* __restrict__ ie4,
                       uint2* __restrict__ h) {
    int i = blockIdx.x * blockDim.x + threadIdx.x;   // over NN*16 float4-groups
    if (i >= NN * 16) return;
    float4 v = (i < NU * 16) ? ue4[i] : ie4[i - NU * 16];
    __half2 a = __float22half2_rn(make_float2(v.x, v.y));
    __half2 b = __float22half2_rn(make_float2(v.z, v.w));
    h[i] = make_uint2(*(unsigned*)&a, *(unsigned*)&b);
}

// ---- SpMM: 2 rows/wave; half-wave per row, l = lane&31 = (e<<2)|d --------
// e = l>>2 (8 edge slots x 2 edges each), d = l&3 (32B dim quarter). Per
// iteration each row gathers 16 edges (32 in flight per wave), both edges of
// a slot FMA into the same 16 accumulators. Branchless tail: index clamped
// to end-1, v zeroed. Reduce over e = 3 recursive-halving shuffle stages;
// lane ends owning consecutive element pair idx, idx+1. Epilogue operand
// prefetched at wave start.
// MODE 0: acc = E32[row] + sum;  1: acc += sum;  2: acc = (acc+sum)*0.25.

template <int MODE>
__global__ void spmm2r_kernel(const int* __restrict__ off, const int2* __restrict__ edges,
                              const uint4* __restrict__ h8,   // fp16 table, [NN][8] x 16B
                              __half* __restrict__ nxtH,      // fp16 output
                              float* __restrict__ acc,
                              const float* __restrict__ ue, const float* __restrict__ ie2) {
    int wave = (blockIdx.x * blockDim.x + threadIdx.x) >> 6;
    int lane = threadIdx.x & 63;
    int l    = lane & 31;         // index within half-wave
    int e    = l >> 2;            // edge slot 0..7
    int d    = l & 3;             // dim quarter (16 halves = 32B)
    int row  = wave * 2 + (lane >> 5);   // NN even: no guard needed

    int start = off[row], end = off[row + 1];

    // final consecutive element pair owned by this lane
    int idx = d * 16 + (((l >> 2) & 1) << 3) + (((l >> 3) & 1) << 2) + (((l >> 4) & 1) << 1);
    size_t o = (size_t)row * DD + idx;

    // prefetch epilogue operand (address depends only on row/lane)
    float b0, b1;
    if (MODE == 0) {
        const float* p = (row < NU) ? ue : ie2;
        b0 = __builtin_nontemporal_load(&p[o]);
        b1 = __builtin_nontemporal_load(&p[o + 1]);
    } else {
        b0 = __builtin_nontemporal_load(&acc[o]);
        b1 = __builtin_nontemporal_load(&acc[o + 1]);
    }

    float s[16];
    #pragma unroll
    for (int k = 0; k < 16; ++k) s[k] = 0.f;

    for (int base = start; base < end; base += 16) {
        int ei0 = base + e;           // slot edge A
        int ei1 = base + 8 + e;       // slot edge B
        int q0 = min(ei0, end - 1);   // branchless clamp (end > base >= start)
        int q1 = min(ei1, end - 1);
        long long w0 = __builtin_nontemporal_load((const long long*)&edges[q0]);
        long long w1 = __builtin_nontemporal_load((const long long*)&edges[q1]);
        int   c0 = (int)(unsigned)w0;
        int   c1 = (int)(unsigned)w1;
        float v0 = (ei0 < end) ? __int_as_float((int)(w0 >> 32)) : 0.f;
        float v1 = (ei1 < end) ? __int_as_float((int)(w1 >> 32)) : 0.f;
        const uint4* hp0 = &h8[(size_t)(unsigned)c0 * 8 + d * 2];
        const uint4* hp1 = &h8[(size_t)(unsigned)c1 * 8 + d * 2];
        uint4 ha = hp0[0];            // both gathers issued together,
        uint4 hb = hp0[1];            // independent chains in flight
        uint4 hc = hp1[0];
        uint4 hd = hp1[1];
        FMA_MIX_LO(s[0],  ha.x, v0); FMA_MIX_HI(s[1],  ha.x, v0);
        FMA_MIX_LO(s[2],  ha.y, v0); FMA_MIX_HI(s[3],  ha.y, v0);
        FMA_MIX_LO(s[4],  ha.z, v0); FMA_MIX_HI(s[5],  ha.z, v0);
        FMA_MIX_LO(s[6],  ha.w, v0); FMA_MIX_HI(s[7],  ha.w, v0);
        FMA_MIX_LO(s[8],  hb.x, v0); FMA_MIX_HI(s[9],  hb.x, v0);
        FMA_MIX_LO(s[10], hb.y, v0); FMA_MIX_HI(s[11], hb.y, v0);
        FMA_MIX_LO(s[12], hb.z, v0); FMA_MIX_HI(s[13], hb.z, v0);
        FMA_MIX_LO(s[14], hb.w, v0); FMA_MIX_HI(s[15], hb.w, v0);
        FMA_MIX_LO(s[0],  hc.x, v1); FMA_MIX_HI(s[1],  hc.x, v1);
        FMA_MIX_LO(s[2],  hc.y, v1); FMA_MIX_HI(s[3],  hc.y, v1);
        FMA_MIX_LO(s[4],  hc.z, v1); FMA_MIX_HI(s[5],  hc.z, v1);
        FMA_MIX_LO(s[6],  hc.w, v1); FMA_MIX_HI(s[7],  hc.w, v1);
        FMA_MIX_LO(s[8],  hd.x, v1); FMA_MIX_HI(s[9],  hd.x, v1);
        FMA_MIX_LO(s[10], hd.y, v1); FMA_MIX_HI(s[11], hd.y, v1);
        FMA_MIX_LO(s[12], hd.z, v1); FMA_MIX_HI(s[13], hd.z, v1);
        FMA_MIX_LO(s[14], hd.w, v1); FMA_MIX_HI(s[15], hd.w, v1);
    }

    // recursive-halving reduce-scatter over the 8 edge slots (lane bits 2..4)
    {
        bool up = (l & 4) != 0;
        #pragma unroll
        for (int k = 0; k < 8; ++k) {
            float keep = up ? s[k + 8] : s[k];
            float give = up ? s[k] : s[k + 8];
            s[k] = keep + __shfl_xor(give, 4);
        }
    }
    {
        bool up = (l & 8) != 0;
        #pragma unroll
        for (int k = 0; k < 4; ++k) {
            float keep = up ? s[k + 4] : s[k];
            float give = up ? s[k] : s[k + 4];
            s[k] = keep + __shfl_xor(give, 8);
        }
    }
    {
        bool up = (l & 16) != 0;
        #pragma unroll
        for (int k = 0; k < 2; ++k) {
            float keep = up ? s[k + 2] : s[k];
            float give = up ? s[k] : s[k + 2];
            s[k] = keep + __shfl_xor(give, 16);
        }
    }
    // lane now owns elements idx, idx+1 with values s[0], s[1]

    if (MODE != 2) {
        __half2 hh = __float22half2_rn(make_float2(s[0], s[1]));
        *(__half2*)&nxtH[o] = hh;
    }
    float r0 = b0 + s[0], r1 = b1 + s[1];
    if (MODE == 2) { r0 *= 0.25f; r1 *= 0.25f; }
    __builtin_nontemporal_store(r0, &acc[o]);
    __builtin_nontemporal_store(r1, &acc[o + 1]);
}

// ---- launch -------------------------------------------------------------

extern "C" void kernel_launch(void* const* d_in, const int* in_sizes, int n_in,
                              void* d_out, int out_size, void* d_ws, size_t ws_size,
                              hipStream_t stream) {
    const float* ue   = (const float*)d_in[0];
    const float* ie   = (const float*)d_in[1];
    const int*   rows = (const int*)d_in[2];
    const int*   cols = (const int*)d_in[3];
    const float* vals = (const float*)d_in[4];
    float* acc = (float*)d_out;

    char* ws = (char*)d_ws;
    size_t p = 0;
    auto alloc = [&](size_t bytes) -> void* {
        p = (p + 255) & ~(size_t)255;
        void* r = ws + p;
        p += bytes;
        return r;
    };
    int2*  edges   = (int2*) alloc((size_t)NE * 8);         // 38.4 MB final CSR
    uint2* h0      = (uint2*)alloc((size_t)NN * 16 * 8);    // 38.4 MB fp16 table
    uint2* h1      = (uint2*)alloc((size_t)NN * 16 * 8);    // 38.4 MB fp16 table
    int*   bcnt    = (int*)  alloc((size_t)NB * 4);
    int*   bbase   = (int*)  alloc((size_t)(NB + 1) * 4);
    int*   gcursor = (int*)  alloc((size_t)NB * 4);
    int*   off     = (int*)  alloc((size_t)(NN + 1) * 4);
    // recs (38.4 MB) aliases h1: dead after fine_sort, h1 first written by spmm<0>
    int2*  recs = (int2*)h1;
    // h2 aliases h0: h0 dead after spmm<0> (spmm<1> gathers h1 only)
    uint2* h2 = h0;

    // 1. CSR build: hist -> scan -> LDS-staged coarse scatter -> fine sort
    hipMemsetAsync(bcnt, 0, (size_t)NB * 4, stream);
    bucket_hist   <<<(NE + CE_HIST - 1) / CE_HIST, 1024, 0, stream>>>(rows, bcnt);
    bucket_scan   <<<1, NB, 0, stream>>>(bcnt, bbase, gcursor);
    bucket_scatter<<<(NE + CE_SCAT - 1) / CE_SCAT, 1024, 0, stream>>>(rows, cols, vals, gcursor, recs);
    fine_sort     <<<NB, 1024, 0, stream>>>(bbase, recs, edges, off);

    // 2. E -> fp16 table (after fine_sort: recs aliases h1, not h0 — safe order)
    const float* ie2 = ie - (size_t)NU * DD;   // pre-shifted item base for concat view
    e_to_h<<<(NN * 16 + 255) / 256, 256, 0, stream>>>(
        (const float4*)ue, (const float4*)ie2 + (size_t)NU * 16, h0);

    // 3. three propagation layers; acc (= d_out) fused, final /4 fused into last
    const int spmm_blocks = NN / 8;   // 2 rows/wave, 4 waves/block
    spmm2r_kernel<0><<<spmm_blocks, 256, 0, stream>>>(off, edges, (const uint4*)h0, (__half*)h1, acc, ue, ie2);
    spmm2r_kernel<1><<<spmm_blocks, 256, 0, stream>>>(off, edges, (const uint4*)h1, (__half*)h2, acc, ue, ie2);
    spmm2r_kernel<2><<<spmm_blocks, 256, 0, stream>>>(off, edges, (const uint4*)h2, (__half*)h1, acc, ue, ie2);
}

// Round 6
// 558.280 us; speedup vs baseline: 1.3103x; 1.0660x over previous
//
#include <hip/hip_runtime.h>
#include <hip/hip_fp16.h>

// LightGCN on MI355X — bucket-sort CSR build + 2-row/wave 16-edge SpMM, fp8 gathers.
// final = (E + A E + A^2 E + A^3 E) / 4,  E = concat(user_emb, item_emb)
//
// R11 changes vs R10 (post-mortem: spmm is at a per-CU outstanding-line
// concurrency roofline: 37.5K lines/CU x ~500cy / ~64 in flight = 122us ==
// measured 120us. More per-wave MLP no longer helps):
//  - gather table in fp8 e4m3 (OCP, gfx950 HW cvt): row = 64B = ONE 64B line
//    per edge (was two). Halves line count AND per-XCD duplicated fetch.
//  - table stores h*4096 (pure exponent shift; E ~ 0.0045 would be subnormal
//    in e4m3 otherwise). vals fp32, accumulation fp32, E-identity term exact
//    fp32; /4096 folded into the acc epilogue. nxtQ write stays in scaled
//    domain (s IS the next table value).
//  - decode: v_cvt_pk_f32_fp8 (2 fp8 -> 2 f32) x8 per 16-value lane slice.
//  - CSR build, lane map, reduce-scatter identical to R10.

#define NU 200000
#define NI 100000
#define NN 300000          // NU + NI
#define DD 64
#define NE 4800000
#define NB 512             // coarse buckets
#define RPB 586            // rows per bucket: 512*586 = 300032 >= NN
#define NRPAD 640          // RPB padded for fine_sort scan
#define CE_HIST 32768      // edges per block, bucket_hist  (147 blocks)
#define CE_SCAT 6144       // edges per block, bucket_scatter (782 blocks)
#define EPT (CE_SCAT / 1024)   // 6 edges per thread in scatter

#define QSCALE 4096.0f
#define QINV   (1.0f / 4096.0f)

typedef float v2f __attribute__((ext_vector_type(2)));

// ---- Phase 1: bucket histogram (LDS pre-aggregated, int4 loads) ---------

__global__ void bucket_hist(const int* __restrict__ rows, int* __restrict__ bcnt) {
    __shared__ int h[NB];
    int tid = threadIdx.x;
    for (int i = tid; i < NB; i += 1024) h[i] = 0;
    __syncthreads();
    const int4* r4 = (const int4*)rows;
    int q0 = blockIdx.x * (CE_HIST / 4);
    for (int k = 0; k < CE_HIST / 4096; ++k) {
        int q = q0 + k * 1024 + tid;
        if (q < NE / 4) {
            int4 r = r4[q];
            atomicAdd(&h[(unsigned)r.x / RPB], 1);
            atomicAdd(&h[(unsigned)r.y / RPB], 1);
            atomicAdd(&h[(unsigned)r.z / RPB], 1);
            atomicAdd(&h[(unsigned)r.w / RPB], 1);
        }
    }
    __syncthreads();
    for (int i = tid; i < NB; i += 1024) {
        int c = h[i];
        if (c) atomicAdd(&bcnt[i], c);
    }
}

// ---- Phase 2a: exclusive scan of 512 bucket counts ----------------------

__global__ void bucket_scan(const int* __restrict__ bcnt, int* __restrict__ bbase,
                            int* __restrict__ gcursor) {
    __shared__ int sh[NB];
    int t = threadIdx.x;          // 512 threads
    int v = bcnt[t];
    sh[t] = v;
    __syncthreads();
    for (int o = 1; o < NB; o <<= 1) {
        int x = (t >= o) ? sh[t - o] : 0;
        __syncthreads();
        sh[t] += x;
        __syncthreads();
    }
    int excl = sh[t] - v;
    bbase[t] = excl;
    gcursor[t] = excl;
    if (t == NB - 1) bbase[NB] = NE;
}

// ---- Phase 2b: LDS-staged coarse sort, coalesced run writeback ----------
// record: x = (rowlocal << 19) | col   (rowlocal < 586 < 2^10, col < 2^19)
//         y = float bits of val

__global__ void bucket_scatter(const int* __restrict__ rows, const int* __restrict__ cols,
                               const float* __restrict__ vals,
                               int* __restrict__ gcursor, int2* __restrict__ recs) {
    __shared__ int  cnt[NB];        // hist, then reused as staging cursor
    __shared__ int  lofs[NB + 1];   // local exclusive scan (+ total sentinel)
    __shared__ int  dlt[NB];        // global_base - local_base per bucket
    __shared__ int2 stg[CE_SCAT];   // 48KB staging
    int tid = threadIdx.x;          // 1024 threads
    if (tid < NB) cnt[tid] = 0;
    __syncthreads();
    int e0 = blockIdx.x * CE_SCAT;
    int r[EPT];
    #pragma unroll
    for (int k = 0; k < EPT; ++k) {
        int e = e0 + k * 1024 + tid;
        r[k] = -1;
        if (e < NE) {
            r[k] = rows[e];
            atomicAdd(&cnt[(unsigned)r[k] / RPB], 1);
        }
    }
    __syncthreads();
    // inclusive scan of cnt into lofs (512 entries, first 512 threads)
    if (tid < NB) lofs[tid] = cnt[tid];
    __syncthreads();
    for (int o = 1; o < NB; o <<= 1) {
        int x = 0;
        if (tid < NB && tid >= o) x = lofs[tid - o];
        __syncthreads();
        if (tid < NB) lofs[tid] += x;
        __syncthreads();
    }
    // convert to exclusive, reserve global run, reset cursor
    if (tid < NB) {
        int incl = lofs[tid];
        int c = cnt[tid];
        int excl = incl - c;
        int gb = c ? atomicAdd(&gcursor[tid], c) : 0;
        lofs[tid] = excl;
        dlt[tid] = gb - excl;
        cnt[tid] = 0;
        if (tid == NB - 1) lofs[NB] = incl;   // total staged in this block
    }
    __syncthreads();
    // stage records bucket-sorted in LDS
    #pragma unroll
    for (int k = 0; k < EPT; ++k) {
        int e = e0 + k * 1024 + tid;
        if (e < NE) {
            int rr = r[k];
            int b = (unsigned)rr / RPB;
            int p = lofs[b] + atomicAdd(&cnt[b], 1);
            int rl = rr - b * RPB;
            stg[p] = make_int2((rl << 19) | cols[e], __float_as_int(vals[e]));
        }
    }
    __syncthreads();
    // coalesced writeback: consecutive i -> consecutive global pos within runs
    int total = lofs[NB];
    for (int i = tid; i < total; i += 1024) {
        int b = 0;
        #pragma unroll
        for (int s = NB >> 1; s > 0; s >>= 1)
            if (lofs[b + s] <= i) b += s;     // greatest b with lofs[b] <= i
        recs[dlt[b] + i] = stg[i];
    }
}

// ---- Phase 3: per-bucket LDS counting sort -> final CSR -----------------

__global__ void fine_sort(const int* __restrict__ bbase, const int2* __restrict__ recs,
                          int2* __restrict__ edges, int* __restrict__ off) {
    __shared__ int cnt[NRPAD];
    __shared__ int scn[NRPAD];
    __shared__ int cur[NRPAD];
    int b = blockIdx.x, tid = threadIdx.x;   // 1024 threads
    int e0 = bbase[b], e1 = bbase[b + 1];
    if (tid < NRPAD) cnt[tid] = 0;
    __syncthreads();
    for (int e = e0 + tid; e < e1; e += 1024)
        atomicAdd(&cnt[recs[e].x >> 19], 1);
    __syncthreads();
    int v = 0;
    if (tid < NRPAD) { v = cnt[tid]; scn[tid] = v; }
    __syncthreads();
    for (int o = 1; o < NRPAD; o <<= 1) {
        int x = 0;
        if (tid < NRPAD && tid >= o) x = scn[tid - o];
        __syncthreads();
        if (tid < NRPAD) scn[tid] += x;
        __syncthreads();
    }
    if (tid < NRPAD) {
        int excl = e0 + scn[tid] - v;
        cur[tid] = excl;
        if (tid < RPB) {
            int row = b * RPB + tid;
            if (row < NN) off[row] = excl;
        }
    }
    if (b == 0 && tid == 0) off[NN] = NE;
    __syncthreads();
    for (int e = e0 + tid; e < e1; e += 1024) {
        int2 rc = recs[e];
        int rl = rc.x >> 19;
        int p = atomicAdd(&cur[rl], 1);
        edges[p] = make_int2(rc.x & 0x7FFFF, rc.y);   // (col, val-bits)
    }
}

// ---- E (fp32 concat view) -> q0 (fp8 e4m3 of value*4096, [NN][64]) ------

__global__ void e_to_q(const float4* __restrict__ ue4, const float4* __restrict__ ie4,
                       uint2* __restrict__ q) {
    int i = blockIdx.x * blockDim.x + threadIdx.x;   // over NN*8 groups of 8 vals
    if (i >= NN * 8) return;
    float4 a, b;
    if (i < NU * 8) { a = ue4[2 * i];            b = ue4[2 * i + 1]; }
    else            { a = ie4[2 * (i - NU * 8)]; b = ie4[2 * (i - NU * 8) + 1]; }
    int p0 = __builtin_amdgcn_cvt_pk_fp8_f32(a.x * QSCALE, a.y * QSCALE, 0, false);
    p0     = __builtin_amdgcn_cvt_pk_fp8_f32(a.z * QSCALE, a.w * QSCALE, p0, true);
    int p1 = __builtin_amdgcn_cvt_pk_fp8_f32(b.x * QSCALE, b.y * QSCALE, 0, false);
    p1     = __builtin_amdgcn_cvt_pk_fp8_f32(b.z * QSCALE, b.w * QSCALE, p1, true);
    q[i] = make_uint2((unsigned)p0, (unsigned)p1);
}

// ---- SpMM: 2 rows/wave; half-wave per row, l = lane&31 = (e<<2)|d --------
// e = l>>2 (8 edge slots x 2 edges each), d = l&3 (16B dim quarter = 16 fp8).
// Per iteration each row gathers 16 edges; each edge's 64B fp8 row is ONE
// cache line read by 4 lanes x 16B. Decode via v_cvt_pk_f32_fp8, fp32 FMA
// into 16 accumulators (scaled-by-4096 domain). Branchless tail. Reduce over
// e = 3 recursive-halving shuffle stages; lane ends owning consecutive pair
// idx, idx+1. Epilogue operand prefetched at wave start.
// MODE 0: acc = E32 + s/4096;  1: acc += s/4096;  2: acc = (acc+s/4096)*.25.

template <int MODE>
__global__ void spmm2r_kernel(const int* __restrict__ off, const int2* __restrict__ edges,
                              const uint4* __restrict__ q4,   // fp8 table, [NN][4] x 16B
                              unsigned char* __restrict__ nxtQ, // fp8 output table
                              float* __restrict__ acc,
                              const float* __restrict__ ue, const float* __restrict__ ie2) {
    int wave = (blockIdx.x * blockDim.x + threadIdx.x) >> 6;
    int lane = threadIdx.x & 63;
    int l    = lane & 31;         // index within half-wave
    int e    = l >> 2;            // edge slot 0..7
    int d    = l & 3;             // dim quarter (16 fp8 = 16B)
    int row  = wave * 2 + (lane >> 5);   // NN even: no guard needed

    int start = off[row], end = off[row + 1];

    // final consecutive element pair owned by this lane
    int idx = d * 16 + (((l >> 2) & 1) << 3) + (((l >> 3) & 1) << 2) + (((l >> 4) & 1) << 1);
    size_t o = (size_t)row * DD + idx;

    // prefetch epilogue operand (address depends only on row/lane)
    float b0, b1;
    if (MODE == 0) {
        const float* p = (row < NU) ? ue : ie2;
        b0 = __builtin_nontemporal_load(&p[o]);
        b1 = __builtin_nontemporal_load(&p[o + 1]);
    } else {
        b0 = __builtin_nontemporal_load(&acc[o]);
        b1 = __builtin_nontemporal_load(&acc[o + 1]);
    }

    float s[16];
    #pragma unroll
    for (int k = 0; k < 16; ++k) s[k] = 0.f;

    for (int base = start; base < end; base += 16) {
        int ei0 = base + e;           // slot edge A
        int ei1 = base + 8 + e;       // slot edge B
        int p0 = min(ei0, end - 1);   // branchless clamp (end > base >= start)
        int p1 = min(ei1, end - 1);
        long long w0 = __builtin_nontemporal_load((const long long*)&edges[p0]);
        long long w1 = __builtin_nontemporal_load((const long long*)&edges[p1]);
        int   c0 = (int)(unsigned)w0;
        int   c1 = (int)(unsigned)w1;
        float v0 = (ei0 < end) ? __int_as_float((int)(w0 >> 32)) : 0.f;
        float v1 = (ei1 < end) ? __int_as_float((int)(w1 >> 32)) : 0.f;
        uint4 qa = q4[(size_t)(unsigned)c0 * 4 + d];   // one 64B line per edge
        uint4 qb = q4[(size_t)(unsigned)c1 * 4 + d];
        {
            v2f f;
            f = __builtin_amdgcn_cvt_pk_f32_fp8((int)qa.x, false); s[0]  += v0 * f.x; s[1]  += v0 * f.y;
            f = __builtin_amdgcn_cvt_pk_f32_fp8((int)qa.x, true ); s[2]  += v0 * f.x; s[3]  += v0 * f.y;
            f = __builtin_amdgcn_cvt_pk_f32_fp8((int)qa.y, false); s[4]  += v0 * f.x; s[5]  += v0 * f.y;
            f = __builtin_amdgcn_cvt_pk_f32_fp8((int)qa.y, true ); s[6]  += v0 * f.x; s[7]  += v0 * f.y;
            f = __builtin_amdgcn_cvt_pk_f32_fp8((int)qa.z, false); s[8]  += v0 * f.x; s[9]  += v0 * f.y;
            f = __builtin_amdgcn_cvt_pk_f32_fp8((int)qa.z, true ); s[10] += v0 * f.x; s[11] += v0 * f.y;
            f = __builtin_amdgcn_cvt_pk_f32_fp8((int)qa.w, false); s[12] += v0 * f.x; s[13] += v0 * f.y;
            f = __builtin_amdgcn_cvt_pk_f32_fp8((int)qa.w, true ); s[14] += v0 * f.x; s[15] += v0 * f.y;
            f = __builtin_amdgcn_cvt_pk_f32_fp8((int)qb.x, false); s[0]  += v1 * f.x; s[1]  += v1 * f.y;
            f = __builtin_amdgcn_cvt_pk_f32_fp8((int)qb.x, true ); s[2]  += v1 * f.x; s[3]  += v1 * f.y;
            f = __builtin_amdgcn_cvt_pk_f32_fp8((int)qb.y, false); s[4]  += v1 * f.x; s[5]  += v1 * f.y;
            f = __builtin_amdgcn_cvt_pk_f32_fp8((int)qb.y, true ); s[6]  += v1 * f.x; s[7]  += v1 * f.y;
            f = __builtin_amdgcn_cvt_pk_f32_fp8((int)qb.z, false); s[8]  += v1 * f.x; s[9]  += v1 * f.y;
            f = __builtin_amdgcn_cvt_pk_f32_fp8((int)qb.z, true ); s[10] += v1 * f.x; s[11] += v1 * f.y;
            f = __builtin_amdgcn_cvt_pk_f32_fp8((int)qb.w, false); s[12] += v1 * f.x; s[13] += v1 * f.y;
            f = __builtin_amdgcn_cvt_pk_f32_fp8((int)qb.w, true ); s[14] += v1 * f.x; s[15] += v1 * f.y;
        }
    }

    // recursive-halving reduce-scatter over the 8 edge slots (lane bits 2..4)
    {
        bool up = (l & 4) != 0;
        #pragma unroll
        for (int k = 0; k < 8; ++k) {
            float keep = up ? s[k + 8] : s[k];
            float give = up ? s[k] : s[k + 8];
            s[k] = keep + __shfl_xor(give, 4);
        }
    }
    {
        bool up = (l & 8) != 0;
        #pragma unroll
        for (int k = 0; k < 4; ++k) {
            float keep = up ? s[k + 4] : s[k];
            float give = up ? s[k] : s[k + 4];
            s[k] = keep + __shfl_xor(give, 8);
        }
    }
    {
        bool up = (l & 16) != 0;
        #pragma unroll
        for (int k = 0; k < 2; ++k) {
            float keep = up ? s[k + 2] : s[k];
            float give = up ? s[k] : s[k + 2];
            s[k] = keep + __shfl_xor(give, 16);
        }
    }
    // lane now owns elements idx, idx+1 with values s[0], s[1] (scaled x4096)

    if (MODE != 2) {
        int packed = __builtin_amdgcn_cvt_pk_fp8_f32(s[0], s[1], 0, false);
        *(unsigned short*)(nxtQ + o) = (unsigned short)packed;   // idx even
    }
    float r0 = b0 + s[0] * QINV, r1 = b1 + s[1] * QINV;
    if (MODE == 2) { r0 *= 0.25f; r1 *= 0.25f; }
    __builtin_nontemporal_store(r0, &acc[o]);
    __builtin_nontemporal_store(r1, &acc[o + 1]);
}

// ---- launch -------------------------------------------------------------

extern "C" void kernel_launch(void* const* d_in, const int* in_sizes, int n_in,
                              void* d_out, int out_size, void* d_ws, size_t ws_size,
                              hipStream_t stream) {
    const float* ue   = (const float*)d_in[0];
    const float* ie   = (const float*)d_in[1];
    const int*   rows = (const int*)d_in[2];
    const int*   cols = (const int*)d_in[3];
    const float* vals = (const float*)d_in[4];
    float* acc = (float*)d_out;

    char* ws = (char*)d_ws;
    size_t p = 0;
    auto alloc = [&](size_t bytes) -> void* {
        p = (p + 255) & ~(size_t)255;
        void* r = ws + p;
        p += bytes;
        return r;
    };
    int2*          edges = (int2*)         alloc((size_t)NE * 8);   // 38.4 MB final CSR
    unsigned char* q0    = (unsigned char*)alloc((size_t)NN * DD);  // 19.2 MB fp8 table
    unsigned char* q1    = (unsigned char*)alloc((size_t)NN * DD);  // 19.2 MB fp8 table
    int*   bcnt    = (int*)  alloc((size_t)NB * 4);
    int*   bbase   = (int*)  alloc((size_t)(NB + 1) * 4);
    int*   gcursor = (int*)  alloc((size_t)NB * 4);
    int*   off     = (int*)  alloc((size_t)(NN + 1) * 4);
    // recs (38.4 MB) aliases q0+q1 (contiguous, NN*64 is 256B-multiple):
    // dead after fine_sort; q0 first written by e_to_q afterwards.
    int2*  recs = (int2*)q0;
    // q2 aliases q0: q0 dead after spmm<0> (spmm<1> gathers q1 only)
    unsigned char* q2 = q0;

    // 1. CSR build: hist -> scan -> LDS-staged coarse scatter -> fine sort
    hipMemsetAsync(bcnt, 0, (size_t)NB * 4, stream);
    bucket_hist   <<<(NE + CE_HIST - 1) / CE_HIST, 1024, 0, stream>>>(rows, bcnt);
    bucket_scan   <<<1, NB, 0, stream>>>(bcnt, bbase, gcursor);
    bucket_scatter<<<(NE + CE_SCAT - 1) / CE_SCAT, 1024, 0, stream>>>(rows, cols, vals, gcursor, recs);
    fine_sort     <<<NB, 1024, 0, stream>>>(bbase, recs, edges, off);

    // 2. E -> fp8 table (after fine_sort: recs aliases q0/q1 — safe order)
    const float* ie2 = ie - (size_t)NU * DD;   // pre-shifted item base for concat view
    e_to_q<<<(NN * 8 + 255) / 256, 256, 0, stream>>>(
        (const float4*)ue, (const float4*)ie2 + (size_t)NU * 16, (uint2*)q0);

    // 3. three propagation layers; acc (= d_out) fused, final /4 fused into last
    const int spmm_blocks = NN / 8;   // 2 rows/wave, 4 waves/block
    spmm2r_kernel<0><<<spmm_blocks, 256, 0, stream>>>(off, edges, (const uint4*)q0, q1, acc, ue, ie2);
    spmm2r_kernel<1><<<spmm_blocks, 256, 0, stream>>>(off, edges, (const uint4*)q1, q2, acc, ue, ie2);
    spmm2r_kernel<2><<<spmm_blocks, 256, 0, stream>>>(off, edges, (const uint4*)q2, q1, acc, ue, ie2);
}

// Round 8
// 543.323 us; speedup vs baseline: 1.3464x; 1.0275x over previous
//
#include <hip/hip_runtime.h>
#include <hip/hip_fp16.h>

// LightGCN on MI355X — bucket-sort CSR build + 2-row/wave 16-edge SpMM, fp8 gathers.
// final = (E + A E + A^2 E + A^3 E) / 4,  E = concat(user_emb, item_emb)
//
// R13 changes vs R12 (post-mortem: R12 FAILED absmax 3.43e-5 > 3.20e-5 —
// fp8-quantized h1,h2 entered the final sum UNDAMPED (~3.4e-5, exactly as a
// 2^-4-rel model predicts). Traffic structure kept; side channel now fp16):
//  - layer0 writes q1 (fp8, gathers) + h1 in fp16 (sequential, 38.4MB).
//  - layer1 gathers q1, writes q2 + updates h16 in place to h1+h2 (same-lane
//    read-modify-write, no hazard). No fp32 acc RMW in layers 0/1.
//  - final layer gathers q2, streams h16 + E, writes acc once.
//    fp16 side error ~2e-6; predicted absmax ~2.0e-5 (R11 was 1.91e-5 PASS).
//  - edge records back to exact 8B (col, fp32 val) — no val13 gamble.
//  - CSR build identical to R11.

#define NU 200000
#define NI 100000
#define NN 300000          // NU + NI
#define DD 64
#define NE 4800000
#define NB 512             // coarse buckets
#define RPB 586            // rows per bucket: 512*586 = 300032 >= NN
#define NRPAD 640          // RPB padded for fine_sort scan
#define CE_HIST 32768      // edges per block, bucket_hist  (147 blocks)
#define CE_SCAT 6144       // edges per block, bucket_scatter (782 blocks)
#define EPT (CE_SCAT / 1024)   // 6 edges per thread in scatter

#define QSCALE 4096.0f
#define QINV   (1.0f / 4096.0f)

typedef float v2f __attribute__((ext_vector_type(2)));

// ---- Phase 1: bucket histogram (LDS pre-aggregated, int4 loads) ---------

__global__ void bucket_hist(const int* __restrict__ rows, int* __restrict__ bcnt) {
    __shared__ int h[NB];
    int tid = threadIdx.x;
    for (int i = tid; i < NB; i += 1024) h[i] = 0;
    __syncthreads();
    const int4* r4 = (const int4*)rows;
    int q0 = blockIdx.x * (CE_HIST / 4);
    for (int k = 0; k < CE_HIST / 4096; ++k) {
        int q = q0 + k * 1024 + tid;
        if (q < NE / 4) {
            int4 r = r4[q];
            atomicAdd(&h[(unsigned)r.x / RPB], 1);
            atomicAdd(&h[(unsigned)r.y / RPB], 1);
            atomicAdd(&h[(unsigned)r.z / RPB], 1);
            atomicAdd(&h[(unsigned)r.w / RPB], 1);
        }
    }
    __syncthreads();
    for (int i = tid; i < NB; i += 1024) {
        int c = h[i];
        if (c) atomicAdd(&bcnt[i], c);
    }
}

// ---- Phase 2a: exclusive scan of 512 bucket counts ----------------------

__global__ void bucket_scan(const int* __restrict__ bcnt, int* __restrict__ bbase,
                            int* __restrict__ gcursor) {
    __shared__ int sh[NB];
    int t = threadIdx.x;          // 512 threads
    int v = bcnt[t];
    sh[t] = v;
    __syncthreads();
    for (int o = 1; o < NB; o <<= 1) {
        int x = (t >= o) ? sh[t - o] : 0;
        __syncthreads();
        sh[t] += x;
        __syncthreads();
    }
    int excl = sh[t] - v;
    bbase[t] = excl;
    gcursor[t] = excl;
    if (t == NB - 1) bbase[NB] = NE;
}

// ---- Phase 2b: LDS-staged coarse sort, coalesced run writeback ----------
// record: x = (rowlocal << 19) | col   (rowlocal < 586 < 2^10, col < 2^19)
//         y = float bits of val

__global__ void bucket_scatter(const int* __restrict__ rows, const int* __restrict__ cols,
                               const float* __restrict__ vals,
                               int* __restrict__ gcursor, int2* __restrict__ recs) {
    __shared__ int  cnt[NB];        // hist, then reused as staging cursor
    __shared__ int  lofs[NB + 1];   // local exclusive scan (+ total sentinel)
    __shared__ int  dlt[NB];        // global_base - local_base per bucket
    __shared__ int2 stg[CE_SCAT];   // 48KB staging
    int tid = threadIdx.x;          // 1024 threads
    if (tid < NB) cnt[tid] = 0;
    __syncthreads();
    int e0 = blockIdx.x * CE_SCAT;
    int r[EPT];
    #pragma unroll
    for (int k = 0; k < EPT; ++k) {
        int e = e0 + k * 1024 + tid;
        r[k] = -1;
        if (e < NE) {
            r[k] = rows[e];
            atomicAdd(&cnt[(unsigned)r[k] / RPB], 1);
        }
    }
    __syncthreads();
    // inclusive scan of cnt into lofs (512 entries, first 512 threads)
    if (tid < NB) lofs[tid] = cnt[tid];
    __syncthreads();
    for (int o = 1; o < NB; o <<= 1) {
        int x = 0;
        if (tid < NB && tid >= o) x = lofs[tid - o];
        __syncthreads();
        if (tid < NB) lofs[tid] += x;
        __syncthreads();
    }
    // convert to exclusive, reserve global run, reset cursor
    if (tid < NB) {
        int incl = lofs[tid];
        int c = cnt[tid];
        int excl = incl - c;
        int gb = c ? atomicAdd(&gcursor[tid], c) : 0;
        lofs[tid] = excl;
        dlt[tid] = gb - excl;
        cnt[tid] = 0;
        if (tid == NB - 1) lofs[NB] = incl;   // total staged in this block
    }
    __syncthreads();
    // stage records bucket-sorted in LDS
    #pragma unroll
    for (int k = 0; k < EPT; ++k) {
        int e = e0 + k * 1024 + tid;
        if (e < NE) {
            int rr = r[k];
            int b = (unsigned)rr / RPB;
            int p = lofs[b] + atomicAdd(&cnt[b], 1);
            int rl = rr - b * RPB;
            stg[p] = make_int2((rl << 19) | cols[e], __float_as_int(vals[e]));
        }
    }
    __syncthreads();
    // coalesced writeback: consecutive i -> consecutive global pos within runs
    int total = lofs[NB];
    for (int i = tid; i < total; i += 1024) {
        int b = 0;
        #pragma unroll
        for (int s = NB >> 1; s > 0; s >>= 1)
            if (lofs[b + s] <= i) b += s;     // greatest b with lofs[b] <= i
        recs[dlt[b] + i] = stg[i];
    }
}

// ---- Phase 3: per-bucket LDS counting sort -> final CSR -----------------

__global__ void fine_sort(const int* __restrict__ bbase, const int2* __restrict__ recs,
                          int2* __restrict__ edges, int* __restrict__ off) {
    __shared__ int cnt[NRPAD];
    __shared__ int scn[NRPAD];
    __shared__ int cur[NRPAD];
    int b = blockIdx.x, tid = threadIdx.x;   // 1024 threads
    int e0 = bbase[b], e1 = bbase[b + 1];
    if (tid < NRPAD) cnt[tid] = 0;
    __syncthreads();
    for (int e = e0 + tid; e < e1; e += 1024)
        atomicAdd(&cnt[recs[e].x >> 19], 1);
    __syncthreads();
    int v = 0;
    if (tid < NRPAD) { v = cnt[tid]; scn[tid] = v; }
    __syncthreads();
    for (int o = 1; o < NRPAD; o <<= 1) {
        int x = 0;
        if (tid < NRPAD && tid >= o) x = scn[tid - o];
        __syncthreads();
        if (tid < NRPAD) scn[tid] += x;
        __syncthreads();
    }
    if (tid < NRPAD) {
        int excl = e0 + scn[tid] - v;
        cur[tid] = excl;
        if (tid < RPB) {
            int row = b * RPB + tid;
            if (row < NN) off[row] = excl;
        }
    }
    if (b == 0 && tid == 0) off[NN] = NE;
    __syncthreads();
    for (int e = e0 + tid; e < e1; e += 1024) {
        int2 rc = recs[e];
        int rl = rc.x >> 19;
        int p = atomicAdd(&cur[rl], 1);
        edges[p] = make_int2(rc.x & 0x7FFFF, rc.y);   // (col, val-bits)
    }
}

// ---- E (fp32 concat view) -> q0 (fp8 e4m3 of value*4096, [NN][64]) ------

__global__ void e_to_q(const float4* __restrict__ ue4, const float4* __restrict__ ie4,
                       uint2* __restrict__ q) {
    int i = blockIdx.x * blockDim.x + threadIdx.x;   // over NN*8 groups of 8 vals
    if (i >= NN * 8) return;
    float4 a, b;
    if (i < NU * 8) { a = ue4[2 * i];            b = ue4[2 * i + 1]; }
    else            { a = ie4[2 * (i - NU * 8)]; b = ie4[2 * (i - NU * 8) + 1]; }
    int p0 = __builtin_amdgcn_cvt_pk_fp8_f32(a.x * QSCALE, a.y * QSCALE, 0, false);
    p0     = __builtin_amdgcn_cvt_pk_fp8_f32(a.z * QSCALE, a.w * QSCALE, p0, true);
    int p1 = __builtin_amdgcn_cvt_pk_fp8_f32(b.x * QSCALE, b.y * QSCALE, 0, false);
    p1     = __builtin_amdgcn_cvt_pk_fp8_f32(b.z * QSCALE, b.w * QSCALE, p1, true);
    q[i] = make_uint2((unsigned)p0, (unsigned)p1);
}

// ---- SpMM: 2 rows/wave; half-wave per row, l = lane&31 = (e<<2)|d --------
// e = l>>2 (8 edge slots x 2 edges each), d = l&3 (16B dim quarter = 16 fp8).
// Per iteration each row gathers 16 edges; each edge's 64B fp8 row is ONE
// cache line read by 4 lanes x 16B. Decode via v_cvt_pk_f32_fp8, fp32 FMA
// into 16 accumulators (scaled-by-4096 domain). Branchless tail. Reduce over
// e = 3 recursive-halving shuffle stages; lane ends owning consecutive pair
// idx, idx+1. Side-sum channel h16 keeps h1 (then h1+h2) in fp16.
// MODE 0: write q1 fp8 + h16 = s/4096.
// MODE 1: write q2 fp8 + h16 += s/4096 (in-place, same-lane RMW).
// MODE 2: acc = (E + h16 + s/4096) * 0.25.

template <int MODE>
__global__ void spmm2r_kernel(const int* __restrict__ off, const int2* __restrict__ edges,
                              const uint4* __restrict__ q4,     // fp8 gather table
                              unsigned char* __restrict__ nxtQ, // fp8 output table
                              __half* __restrict__ h16,         // fp16 side-sum
                              float* __restrict__ acc,
                              const float* __restrict__ ue, const float* __restrict__ ie2) {
    int wave = (blockIdx.x * blockDim.x + threadIdx.x) >> 6;
    int lane = threadIdx.x & 63;
    int l    = lane & 31;         // index within half-wave
    int e    = l >> 2;            // edge slot 0..7
    int d    = l & 3;             // dim quarter (16 fp8 = 16B)
    int row  = wave * 2 + (lane >> 5);   // NN even: no guard needed

    int start = off[row], end = off[row + 1];

    // final consecutive element pair owned by this lane
    int idx = d * 16 + (((l >> 2) & 1) << 3) + (((l >> 3) & 1) << 2) + (((l >> 4) & 1) << 1);
    size_t o = (size_t)row * DD + idx;

    // prefetch epilogue operands (addresses depend only on row/lane)
    float b0 = 0.f, b1 = 0.f;
    float2 hf = make_float2(0.f, 0.f);
    if (MODE >= 1) {
        unsigned hw = __builtin_nontemporal_load((const unsigned*)(h16 + o));
        hf = __half22float2(*(__half2*)&hw);
    }
    if (MODE == 2) {
        const float* p = (row < NU) ? ue : ie2;
        b0 = __builtin_nontemporal_load(&p[o]);
        b1 = __builtin_nontemporal_load(&p[o + 1]);
    }

    float s[16];
    #pragma unroll
    for (int k = 0; k < 16; ++k) s[k] = 0.f;

    for (int base = start; base < end; base += 16) {
        int ei0 = base + e;           // slot edge A
        int ei1 = base + 8 + e;       // slot edge B
        int p0 = min(ei0, end - 1);   // branchless clamp (end > base >= start)
        int p1 = min(ei1, end - 1);
        long long w0 = __builtin_nontemporal_load((const long long*)&edges[p0]);
        long long w1 = __builtin_nontemporal_load((const long long*)&edges[p1]);
        unsigned c0 = (unsigned)w0 & 0x7FFFFu;
        unsigned c1 = (unsigned)w1 & 0x7FFFFu;
        float v0 = (ei0 < end) ? __int_as_float((int)(w0 >> 32)) : 0.f;
        float v1 = (ei1 < end) ? __int_as_float((int)(w1 >> 32)) : 0.f;
        uint4 qa = q4[(size_t)c0 * 4 + d];   // one 64B line per edge
        uint4 qb = q4[(size_t)c1 * 4 + d];
        {
            v2f f;
            f = __builtin_amdgcn_cvt_pk_f32_fp8((int)qa.x, false); s[0]  += v0 * f.x; s[1]  += v0 * f.y;
            f = __builtin_amdgcn_cvt_pk_f32_fp8((int)qa.x, true ); s[2]  += v0 * f.x; s[3]  += v0 * f.y;
            f = __builtin_amdgcn_cvt_pk_f32_fp8((int)qa.y, false); s[4]  += v0 * f.x; s[5]  += v0 * f.y;
            f = __builtin_amdgcn_cvt_pk_f32_fp8((int)qa.y, true ); s[6]  += v0 * f.x; s[7]  += v0 * f.y;
            f = __builtin_amdgcn_cvt_pk_f32_fp8((int)qa.z, false); s[8]  += v0 * f.x; s[9]  += v0 * f.y;
            f = __builtin_amdgcn_cvt_pk_f32_fp8((int)qa.z, true ); s[10] += v0 * f.x; s[11] += v0 * f.y;
            f = __builtin_amdgcn_cvt_pk_f32_fp8((int)qa.w, false); s[12] += v0 * f.x; s[13] += v0 * f.y;
            f = __builtin_amdgcn_cvt_pk_f32_fp8((int)qa.w, true ); s[14] += v0 * f.x; s[15] += v0 * f.y;
            f = __builtin_amdgcn_cvt_pk_f32_fp8((int)qb.x, false); s[0]  += v1 * f.x; s[1]  += v1 * f.y;
            f = __builtin_amdgcn_cvt_pk_f32_fp8((int)qb.x, true ); s[2]  += v1 * f.x; s[3]  += v1 * f.y;
            f = __builtin_amdgcn_cvt_pk_f32_fp8((int)qb.y, false); s[4]  += v1 * f.x; s[5]  += v1 * f.y;
            f = __builtin_amdgcn_cvt_pk_f32_fp8((int)qb.y, true ); s[6]  += v1 * f.x; s[7]  += v1 * f.y;
            f = __builtin_amdgcn_cvt_pk_f32_fp8((int)qb.z, false); s[8]  += v1 * f.x; s[9]  += v1 * f.y;
            f = __builtin_amdgcn_cvt_pk_f32_fp8((int)qb.z, true ); s[10] += v1 * f.x; s[11] += v1 * f.y;
            f = __builtin_amdgcn_cvt_pk_f32_fp8((int)qb.w, false); s[12] += v1 * f.x; s[13] += v1 * f.y;
            f = __builtin_amdgcn_cvt_pk_f32_fp8((int)qb.w, true ); s[14] += v1 * f.x; s[15] += v1 * f.y;
        }
    }

    // recursive-halving reduce-scatter over the 8 edge slots (lane bits 2..4)
    {
        bool up = (l & 4) != 0;
        #pragma unroll
        for (int k = 0; k < 8; ++k) {
            float keep = up ? s[k + 8] : s[k];
            float give = up ? s[k] : s[k + 8];
            s[k] = keep + __shfl_xor(give, 4);
        }
    }
    {
        bool up = (l & 8) != 0;
        #pragma unroll
        for (int k = 0; k < 4; ++k) {
            float keep = up ? s[k + 4] : s[k];
            float give = up ? s[k] : s[k + 4];
            s[k] = keep + __shfl_xor(give, 8);
        }
    }
    {
        bool up = (l & 16) != 0;
        #pragma unroll
        for (int k = 0; k < 2; ++k) {
            float keep = up ? s[k + 2] : s[k];
            float give = up ? s[k] : s[k + 2];
            s[k] = keep + __shfl_xor(give, 16);
        }
    }
    // lane now owns elements idx, idx+1 with values s[0], s[1] (scaled x4096)

    if (MODE != 2) {
        int packed = __builtin_amdgcn_cvt_pk_fp8_f32(s[0], s[1], 0, false);
        unsigned short us = (unsigned short)packed;
        __builtin_nontemporal_store(us, (unsigned short*)(nxtQ + o));
        float n0 = hf.x + s[0] * QINV;       // MODE 0: hf = 0
        float n1 = hf.y + s[1] * QINV;
        __half2 hh = __float22half2_rn(make_float2(n0, n1));
        __builtin_nontemporal_store(*(unsigned*)&hh, (unsigned*)(h16 + o));
    } else {
        float r0 = (b0 + hf.x + s[0] * QINV) * 0.25f;
        float r1 = (b1 + hf.y + s[1] * QINV) * 0.25f;
        __builtin_nontemporal_store(r0, &acc[o]);
        __builtin_nontemporal_store(r1, &acc[o + 1]);
    }
}

// ---- launch -------------------------------------------------------------

extern "C" void kernel_launch(void* const* d_in, const int* in_sizes, int n_in,
                              void* d_out, int out_size, void* d_ws, size_t ws_size,
                              hipStream_t stream) {
    const float* ue   = (const float*)d_in[0];
    const float* ie   = (const float*)d_in[1];
    const int*   rows = (const int*)d_in[2];
    const int*   cols = (const int*)d_in[3];
    const float* vals = (const float*)d_in[4];
    float* acc = (float*)d_out;

    char* ws = (char*)d_ws;
    size_t p = 0;
    auto alloc = [&](size_t bytes) -> void* {
        p = (p + 255) & ~(size_t)255;
        void* r = ws + p;
        p += bytes;
        return r;
    };
    int2*          edges = (int2*)         alloc((size_t)NE * 8);       // 38.4 MB CSR
    unsigned char* q0    = (unsigned char*)alloc((size_t)NN * DD);      // 19.2 MB fp8
    unsigned char* q1    = (unsigned char*)alloc((size_t)NN * DD);      // 19.2 MB fp8
    __half*        h16   = (__half*)       alloc((size_t)NN * DD * 2);  // 38.4 MB fp16 side-sum
    int*   bcnt    = (int*)  alloc((size_t)NB * 4);
    int*   bbase   = (int*)  alloc((size_t)(NB + 1) * 4);
    int*   gcursor = (int*)  alloc((size_t)NB * 4);
    int*   off     = (int*)  alloc((size_t)(NN + 1) * 4);
    // recs (38.4 MB) aliases q0+q1 (contiguous, both 256B-multiples): dead
    // after fine_sort; q0 first written by e_to_q afterwards.
    int2*  recs = (int2*)q0;
    // q2 aliases q0: q0 dead after spmm<0> (spmm<1> gathers q1 only; final
    // gathers q2(=q0) and streams h16 — q1 never read again).
    unsigned char* q2 = q0;

    // 1. CSR build: hist -> scan -> LDS-staged coarse scatter -> fine sort
    hipMemsetAsync(bcnt, 0, (size_t)NB * 4, stream);
    bucket_hist   <<<(NE + CE_HIST - 1) / CE_HIST, 1024, 0, stream>>>(rows, bcnt);
    bucket_scan   <<<1, NB, 0, stream>>>(bcnt, bbase, gcursor);
    bucket_scatter<<<(NE + CE_SCAT - 1) / CE_SCAT, 1024, 0, stream>>>(rows, cols, vals, gcursor, recs);
    fine_sort     <<<NB, 1024, 0, stream>>>(bbase, recs, edges, off);

    // 2. E -> fp8 table (after fine_sort: recs aliases q0/q1 — safe order)
    const float* ie2 = ie - (size_t)NU * DD;   // pre-shifted item base for concat view
    e_to_q<<<(NN * 8 + 255) / 256, 256, 0, stream>>>(
        (const float4*)ue, (const float4*)ie2 + (size_t)NU * 16, (uint2*)q0);

    // 3. three propagation layers; fp16 side-sum carries h1 then h1+h2,
    //    final layer composes acc = (E + h16 + h3)/4 with one fp32 write.
    const int spmm_blocks = NN / 8;   // 2 rows/wave, 4 waves/block
    spmm2r_kernel<0><<<spmm_blocks, 256, 0, stream>>>(off, edges, (const uint4*)q0, q1,
                                                      h16, acc, ue, ie2);
    spmm2r_kernel<1><<<spmm_blocks, 256, 0, stream>>>(off, edges, (const uint4*)q1, q2,
                                                      h16, acc, ue, ie2);
    spmm2r_kernel<2><<<spmm_blocks, 256, 0, stream>>>(off, edges, (const uint4*)q2, nullptr,
                                                      h16, acc, ue, ie2);
}